// Round 9
// baseline (313.742 us; speedup 1.0000x reference)
//
#include <hip/hip_runtime.h>

#define DEV __device__ __forceinline__

typedef __attribute__((ext_vector_type(4))) float f32x4;
typedef __attribute__((ext_vector_type(2))) float f32x2;
typedef __attribute__((ext_vector_type(8))) short bf16x8;

// Shapes: E=16, D=1024, ED=512, NB=8, DB=64, R=2, F=256, N=32768, C=2048

// ---------- helpers ----------
DEV unsigned short f2bf(float f) {
  union { float f; unsigned u; } v; v.f = f;
  unsigned r = v.u + 0x7fffu + ((v.u >> 16) & 1u);
  return (unsigned short)(r >> 16);
}

DEV unsigned pk2bf(float lo, float hi) {  // v_cvt_pk_bf16_f32 (RNE)
  unsigned r;
  asm("v_cvt_pk_bf16_f32 %0, %1, %2" : "=v"(r) : "v"(lo), "v"(hi));
  return r;
}
DEV unsigned short f2bf1(float v) { return (unsigned short)pk2bf(v, v); }

DEV float bf2f(unsigned short b) {
  union { unsigned u; float f; } v; v.u = ((unsigned)b) << 16; return v.f;
}

DEV float frcp(float x) { return __builtin_amdgcn_rcpf(x); }

// raw barrier: NO implicit vmcnt drain. "memory" clobber = compiler fence.
DEV void sbar() { asm volatile("s_barrier" ::: "memory"); }
DEV void wait_lgkm0() { asm volatile("s_waitcnt lgkmcnt(0)" ::: "memory"); }
DEV void wait_vm0() { asm volatile("s_waitcnt vmcnt(0)" ::: "memory"); }

DEV void async16(const unsigned short* g, unsigned short* l) {
  __builtin_amdgcn_global_load_lds(
      (__attribute__((address_space(1))) const unsigned int*)g,
      (__attribute__((address_space(3))) unsigned int*)l, 16, 0, 0);
}

// Tiled global layout for GEMM operands: element (n,k) of an [N][K] panel at
//   (n>>3)*8K + (k>>3)*64 + (n&7)*8 + (k&7)
DEV long tiled_off(long n, int k, int K) {
  return (n >> 3) * (8L * K) + (long)(((k >> 3) * 64) + ((int)(n & 7)) * 8 + (k & 7));
}

// frag read from a tiled 32-k LDS subtile (bf16)
DEV bf16x8 ld_frag(const char* s, int row, int hi) {
  return *(const bf16x8*)(s + ((row >> 3) * 512 + hi * 128 + (row & 7) * 16));
}

// ---------- Cayley table at compile time ----------
__host__ __device__ constexpr int km_(int i) { return i==0?0:i==1?1:i==2?2:i==3?4:i==4?3:i==5?5:i==6?6:7; }
__host__ __device__ constexpr int pc_(int x) { int c = 0; while (x) { c += x & 1; x >>= 1; } return c; }
__host__ __device__ constexpr int KIDX(int i, int j) { return km_(km_(i) ^ km_(j)); }
__host__ __device__ constexpr int CSGN(int i, int j) {
  int a = km_(i), b = km_(j), aa = a >> 1, s = 0;
  while (aa) { s += pc_(aa & b); aa >>= 1; }
  return (s & 1) ? -1 : 1;
}
__host__ __device__ constexpr int PIDX(int i, int j) {  // i<=j
  return 8 * i - (i * (i - 1)) / 2 + (j - i);
}

// ---------- prep bodies (merged into ONE dispatch) ----------

DEV void geoprep_body(const float* __restrict__ iw, const float* __restrict__ gg,
                      float* __restrict__ wcomb, int er) {
  const float* w = iw + er * 64;
  float gate = frcp(1.f + __expf(-gg[er]));
  float* c = wcomb + er * 40;
  int p = 0;
  for (int i = 0; i < 8; ++i)
    for (int j = i; j < 8; ++j) {
      float v = (float)CSGN(i, j) * frcp(1.f + __expf(-w[i * 8 + j]));
      if (j > i) v += (float)CSGN(j, i) * frcp(1.f + __expf(-w[j * 8 + i]));
      c[p++] = gate * v;
    }
  c[36] = 1.f - gate;
}

// small transpose: in (Rr,Cc) fp32 (batch bz) -> (Cc,Rr) bf16.
// TI=0 linear; TI=1: k ^= (row&7)<<3 (needs Rr==64).
template<int TI>
DEV void transpose_body(const float* __restrict__ in, unsigned short* __restrict__ out,
                        int Rr, int Cc, int bx, int by, int bz, int tid, char* sbuf) {
  unsigned short (*tile)[33] = (unsigned short (*)[33])sbuf;
  const float* ib = in + (long)bz * Rr * Cc;
  unsigned short* ob = out + (long)bz * Rr * Cc;
  int r0 = by * 32, c0 = bx * 32;
  int tr = tid >> 5, tc = tid & 31;
#pragma unroll
  for (int i = 0; i < 4; ++i) {
    int r = tr + i * 8;
    tile[r][tc] = f2bf(ib[(long)(r0 + r) * Cc + c0 + tc]);
  }
  __syncthreads();
#pragma unroll
  for (int i = 0; i < 4; ++i) {
    int c = tr + i * 8;
    int row = c0 + c;
    int k = r0 + tc;
    if (TI == 0) ob[(long)row * Rr + k] = tile[tc][c];
    else ob[(long)row * Rr + (k ^ ((row & 7) << 3))] = tile[tc][c];
  }
}

// big convert+transpose for pin/pout: in [Rr k][Cc n] fp32 -> out tiled bf16 [n][k].
DEV void trans_big_body(const float* __restrict__ in, unsigned short* __restrict__ out,
                        int Rr, int Cc, int bx, int by, int bz, int tid, char* sbuf) {
  float (*t)[64] = (float (*)[64])sbuf;
  const float* ib = in + (long)bz * Rr * Cc;
  unsigned short* ob = out + (long)bz * (long)Rr * Cc;
  int k0 = by * 64, n0 = bx * 64;
#pragma unroll
  for (int p = 0; p < 4; ++p) {
    int idx = p * 256 + tid;
    int kr = idx >> 4, nc = (idx & 15) * 4;
    *(float4*)&t[kr][nc] = *(const float4*)(ib + (long)(k0 + kr) * Cc + n0 + nc);
  }
  __syncthreads();
#pragma unroll
  for (int p = 0; p < 2; ++p) {
    int idx = p * 256 + tid;
    int n = idx & 63, kc = idx >> 6;       // kc 0..7
    float v[8];
#pragma unroll
    for (int u = 0; u < 8; ++u) v[u] = t[kc * 8 + u][n];
    uint4 o;
    o.x = pk2bf(v[0], v[1]); o.y = pk2bf(v[2], v[3]);
    o.z = pk2bf(v[4], v[5]); o.w = pk2bf(v[6], v[7]);
    *(uint4*)(ob + tiled_off(n0 + n, k0 + kc * 8, Rr)) = o;
  }
}

// ONE dispatch for all prep: blocks 0..2047 pinT, 2048..4095 poutT,
// 4096..4607 wgT, 4608..5119 wuT, 5120..5631 wdT, 5632 geoprep.
__global__ __launch_bounds__(256) void prep_k(
    const float* __restrict__ pin, const float* __restrict__ pout,
    const float* __restrict__ fg, const float* __restrict__ fu,
    const float* __restrict__ fd, const float* __restrict__ iw,
    const float* __restrict__ gg,
    unsigned short* __restrict__ pinT, unsigned short* __restrict__ poutT,
    unsigned short* __restrict__ wgT, unsigned short* __restrict__ wuT,
    unsigned short* __restrict__ wdT, float* __restrict__ wcomb) {
  __shared__ char sbuf[16384];
  int b = blockIdx.x, tid = threadIdx.x;
  if (b < 2048) {
    trans_big_body(pin, pinT, 1024, 512, b & 7, (b >> 3) & 15, b >> 7, tid, sbuf);
  } else if (b < 4096) {
    int j = b - 2048;
    trans_big_body(pout, poutT, 512, 1024, j & 15, (j >> 4) & 7, j >> 7, tid, sbuf);
  } else if (b < 4608) {
    int j = b - 4096;
    transpose_body<1>(fg, wgT, 64, 256, j & 7, (j >> 3) & 1, j >> 4, tid, sbuf);
  } else if (b < 5120) {
    int j = b - 4608;
    transpose_body<1>(fu, wuT, 64, 256, j & 7, (j >> 3) & 1, j >> 4, tid, sbuf);
  } else if (b < 5632) {
    int j = b - 5120;
    transpose_body<0>(fd, wdT, 256, 64, j & 1, (j >> 1) & 7, j >> 4, tid, sbuf);
  } else {
    if (tid < 32) geoprep_body(iw, gg, wcomb, tid);
  }
}

// GEMM1 (convert FUSED): mvB(bf16, linear [token][512]) = x @ Pin^T per expert.
// 256x256 tile, BK=64 in two 32-sub-phases. B staged via async16 from tiled
// pinT; A staged from x fp32 directly (reg-load -> cvt -> ds_write, T14 split).
__global__ __launch_bounds__(512, 1) void gemm_in_k(const float* __restrict__ X,
                                                    const unsigned short* __restrict__ Bw,
                                                    unsigned short* __restrict__ MvB,
                                                    const int* __restrict__ offs) {
  extern __shared__ char smem[];    // [2 buf][ A 32K | B 32K ], each op as 2 x 16K ksub
  int bid = blockIdx.x;             // 256 blocks
  int wg = (bid & 7) * 32 + (bid >> 3);      // XCD swizzle (256 % 8 == 0)
  int e = wg >> 4, rem = wg & 15, bm = rem >> 1, bn = rem & 1;
  int tid = threadIdx.x, wid = tid >> 6, lane = tid & 63;
  int wm = (wid >> 2) * 128, wn = (wid & 3) * 64;
  int ri = lane & 15, hi = lane >> 4;
  long rowbase = (long)offs[e] + bm * 256;   // A row base (x fp32 linear)
  long bw = (long)e * 64 + bn * 32;          // B window base (pinT tiled, K=1024)

  // phase p = t*2+s (t=K-tile 0..15, s=32-k sub 0..1)
  auto STGB = [&](int p) {
    int t = p >> 1, s = p & 1, b = t & 1;
    char* dst = smem + b * 65536 + 32768 + s * 16384;
#pragma unroll
    for (int i = 0; i < 2; ++i) {
      int d = i * 512 + tid;
      async16(Bw + (bw + (d >> 5)) * 8192 +
                  (long)((t * 8 + s * 4 + ((d >> 3) & 3)) * 64 + (d & 7) * 8),
              (unsigned short*)(dst + d * 16));
    }
  };
  auto A_LOAD = [&](int p, float4 ar[2][2]) {
    int t = p >> 1, s = p & 1;
#pragma unroll
    for (int i = 0; i < 2; ++i) {
      int d = i * 512 + tid;
      const float* src = X + (rowbase + ((d >> 5) * 8 + (d & 7))) * 1024 +
                         t * 64 + s * 32 + ((d >> 3) & 3) * 8;
      ar[i][0] = *(const float4*)src;
      ar[i][1] = *(const float4*)(src + 4);
    }
  };
  auto A_WRITE = [&](int p, float4 ar[2][2]) {
    int t = p >> 1, s = p & 1, b = t & 1;
    char* dst = smem + b * 65536 + s * 16384;
#pragma unroll
    for (int i = 0; i < 2; ++i) {
      int d = i * 512 + tid;
      uint4 o;
      o.x = pk2bf(ar[i][0].x, ar[i][0].y);
      o.y = pk2bf(ar[i][0].z, ar[i][0].w);
      o.z = pk2bf(ar[i][1].x, ar[i][1].y);
      o.w = pk2bf(ar[i][1].z, ar[i][1].w);
      *(uint4*)(dst + d * 16) = o;
    }
  };

  f32x4 acc[8][4];
#pragma unroll
  for (int i = 0; i < 8; ++i)
#pragma unroll
    for (int j = 0; j < 4; ++j) acc[i][j] = (f32x4){0.f, 0.f, 0.f, 0.f};

  // prologue: phases 0 and 1 staged (A via regs, B via async16)
  float4 ar[2][2];
  A_LOAD(0, ar); STGB(0); STGB(1);
  A_WRITE(0, ar);                 // compiler auto-waits the A regs
  A_LOAD(1, ar);
  A_WRITE(1, ar);
  wait_lgkm0();

#pragma unroll 2
  for (int p = 0; p < 32; ++p) {
    int t = p >> 1, s = p & 1, c = t & 1;
    if (p < 30) { A_LOAD(p + 2, ar); STGB(p + 2); }
    if (p < 30) asm volatile("s_waitcnt vmcnt(8)" ::: "memory");
    else if (p == 30) asm volatile("s_waitcnt vmcnt(2)" ::: "memory");
    else asm volatile("s_waitcnt vmcnt(0)" ::: "memory");
    sbar();
    const char* cA = smem + c * 65536 + s * 16384;
    const char* cB = smem + c * 65536 + 32768 + s * 16384;
    bf16x8 a[8], b[4];
#pragma unroll
    for (int i = 0; i < 8; ++i) a[i] = ld_frag(cA, wm + i * 16 + ri, hi);
#pragma unroll
    for (int j = 0; j < 4; ++j) b[j] = ld_frag(cB, wn + j * 16 + ri, hi);
    __builtin_amdgcn_s_setprio(1);
#pragma unroll
    for (int i = 0; i < 8; ++i)
#pragma unroll
      for (int j = 0; j < 4; ++j)
        acc[i][j] = __builtin_amdgcn_mfma_f32_16x16x32_bf16(a[i], b[j], acc[i][j], 0, 0, 0);
    __builtin_amdgcn_s_setprio(0);
    if (p < 30) A_WRITE(p + 2, ar);
    wait_lgkm0();
  }

  unsigned short* Cb = MvB + ((long)e * 2048 + (long)bm * 256) * 512 + bn * 256;
#pragma unroll
  for (int i = 0; i < 8; ++i)
#pragma unroll
    for (int j = 0; j < 4; ++j)
#pragma unroll
      for (int rr = 0; rr < 4; ++rr)
        Cb[(long)(wm + i * 16 + hi * 4 + rr) * 512 + wn + j * 16 + ri] =
            f2bf1(acc[i][j][rr]);
}

// ---------- merged 2-round fused kernel: 8 TOKENS PER WAVE, REG RESIDUAL ----------
// 32 tokens/block, 256 threads = 4 waves; each wave owns 8 tokens (64 trows,
// 4 trow-tiles) END-TO-END. r8 lesson: 8tok/2blk gained only 6% over 4tok/3blk
// because occupancy fell with LDS. Fix: residual state sMv (32K) -> 32 VGPRs
// (uint4 uv[8], bf16-packed, already in P1a lane layout). The P5 frag->token
// transpose goes through sFH, which is DEAD at P5 (last h consumed by final
// P4): write bf16 deltas, lgkm, read back in (t8,q) layout, add in regs.
// LDS 48K -> 3 blocks/CU (144K) at __launch_bounds__(256,3): VGPR cap 170,
// demand ~140 (104 + 32 uv), no spill.
//   sFH  @0     32K: 4 waves x 8K [64 row][128B] xor swz (flat -> h -> P5 scr)
//   sW   @32K   16K: dbuf x (Wg 4K | Wu 4K) eighth (swizzle baked in global)
__global__ __launch_bounds__(256, 3) void rounds_k(
    const unsigned short* __restrict__ MvB, const unsigned short* __restrict__ WgT,
    const unsigned short* __restrict__ WuT, const unsigned short* __restrict__ WdT,
    const float* __restrict__ wcomb, const float* __restrict__ lnw,
    const float* __restrict__ lnb, unsigned short* __restrict__ Mvb) {
  extern __shared__ char smem[];
  int tid = threadIdx.x, wid = tid >> 6, lane = tid & 63;
  char* sFH = smem + wid * 8192;            // wave-private [64 row][128B]
  char* sW  = smem + 32768;                 // dbuf 2 x 8K (Wg 4K | Wu 4K)

  int bid = blockIdx.x;
  int wg = (bid & 7) * 128 + (bid >> 3);    // XCD swizzle (1024 % 8 == 0)
  int e = wg >> 6, bx = wg & 63;

  int t8 = lane >> 3, q = lane & 7;         // P1/P5 coords: token-in-wave, d-octet
  int ri = lane & 15, hi = lane >> 4;       // frag coords
  int sw = (ri & 7) << 4;

  // stage global eighth i8 (0..15; round = i8>>3, slice = i8&7)
  auto STAGE = [&](int i8) {
    long base = (long)(e * 2 + (i8 >> 3)) * 16384 + (i8 & 7) * 2048;
    char* dst = sW + (i8 & 1) * 8192;
    async16(WgT + base + tid * 8, (unsigned short*)(dst + tid * 16));
    async16(WuT + base + tid * 8, (unsigned short*)(dst + 4096 + tid * 16));
  };
  STAGE(0);   // prologue: lands under P1 of round 0

  // ---- persistent residual state in regs: uv[i] = (token t8, blade i, d 8q..8q+7) ----
  uint4 uv[8];
  {
    long base = ((long)e * 2048 + bx * 32 + wid * 8 + t8) * 512 + 8 * q;
#pragma unroll
    for (int i = 0; i < 8; ++i)
      uv[i] = *(const uint4*)(MvB + base + i * 64);
  }

#pragma unroll 1
  for (int r = 0; r < 2; ++r) {
    int er = e * 2 + r;
    const unsigned short* wd = WdT + (long)er * 16384;  // [64 dout][256 F]

    // ---- P1a: unpack reg-resident mv (two f32x4 halves per blade) ----
    f32x4 mv[2][8];
#pragma unroll
    for (int i = 0; i < 8; ++i) {
      mv[0][i] = (f32x4){bf2f((unsigned short)(uv[i].x & 0xffff)),
                         bf2f((unsigned short)(uv[i].x >> 16)),
                         bf2f((unsigned short)(uv[i].y & 0xffff)),
                         bf2f((unsigned short)(uv[i].y >> 16))};
      mv[1][i] = (f32x4){bf2f((unsigned short)(uv[i].z & 0xffff)),
                         bf2f((unsigned short)(uv[i].z >> 16)),
                         bf2f((unsigned short)(uv[i].w & 0xffff)),
                         bf2f((unsigned short)(uv[i].w >> 16))};
    }

    // ---- P1b: geo + mix + LN(64) -> sFH (packed math; wave-private) ----
    {
      const float* C = wcomb + er * 40;
      f32x4 g[2][8];
#pragma unroll
      for (int hf = 0; hf < 2; ++hf)
#pragma unroll
        for (int k = 0; k < 8; ++k) g[hf][k] = (f32x4){0.f, 0.f, 0.f, 0.f};
#pragma unroll
      for (int i = 0; i < 8; ++i)
#pragma unroll
        for (int j = i; j < 8; ++j) {
          float cc = C[PIDX(i, j)];
          const int k = KIDX(i, j);
          g[0][k] += cc * (mv[0][i] * mv[0][j]);
          g[1][k] += cc * (mv[1][i] * mv[1][j]);
        }
      float omg = C[36];
#pragma unroll
      for (int hf = 0; hf < 2; ++hf)
#pragma unroll
        for (int k = 0; k < 8; ++k) g[hf][k] = omg * mv[hf][k] + g[hf][k];
      float4 lwa = *(const float4*)(lnw + (long)er * 64 + 8 * q);
      float4 lwb = *(const float4*)(lnw + (long)er * 64 + 8 * q + 4);
      float4 lba = *(const float4*)(lnb + (long)er * 64 + 8 * q);
      float4 lbb = *(const float4*)(lnb + (long)er * 64 + 8 * q + 4);
      f32x4 lwvA = (f32x4){lwa.x, lwa.y, lwa.z, lwa.w};
      f32x4 lwvB = (f32x4){lwb.x, lwb.y, lwb.z, lwb.w};
      f32x4 lbvA = (f32x4){lba.x, lba.y, lba.z, lba.w};
      f32x4 lbvB = (f32x4){lbb.x, lbb.y, lbb.z, lbb.w};
#pragma unroll
      for (int bh = 0; bh < 2; ++bh) {
        f32x2 red[4];
#pragma unroll
        for (int k = 0; k < 4; ++k) {
          f32x4 a = g[0][bh * 4 + k], b = g[1][bh * 4 + k];
          red[k].x = ((a.x + a.y) + (a.z + a.w)) + ((b.x + b.y) + (b.z + b.w));
          red[k].y = (fmaf(a.x, a.x, a.y * a.y) + fmaf(a.z, a.z, a.w * a.w)) +
                     (fmaf(b.x, b.x, b.y * b.y) + fmaf(b.z, b.z, b.w * b.w));
        }
#pragma unroll
        for (int off = 4; off >= 1; off >>= 1)
#pragma unroll
          for (int t = 0; t < 4; ++t) {
            f32x2 o;
            o.x = __shfl_xor(red[t].x, off);
            o.y = __shfl_xor(red[t].y, off);
            red[t] += o;
          }
#pragma unroll
        for (int k = 0; k < 4; ++k) {
          int kk = bh * 4 + k;
          float mean = red[k].x * (1.f / 64.f);
          float var = red[k].y * (1.f / 64.f) - mean * mean;
          float rs = rsqrtf(var + 1e-5f);
          f32x4 ovA = ((g[0][kk] - mean) * rs) * lwvA + lbvA;
          f32x4 ovB = ((g[1][kk] - mean) * rs) * lwvB + lbvB;
          uint4 pv;
          pv.x = pk2bf(ovA.x, ovA.y);
          pv.y = pk2bf(ovA.z, ovA.w);
          pv.z = pk2bf(ovB.x, ovB.y);
          pv.w = pk2bf(ovB.z, ovB.w);
          int row = t8 * 8 + kk;                    // row&7 == kk
          *(uint4*)(sFH + row * 128 + ((16 * q) ^ (kk << 4))) = pv;
        }
      }
    }
    wait_lgkm0();   // own-wave flat writes done (cross-LANE reads next)

    // ---- hoist flat B-frags to regs (sFH gets reused for h afterwards) ----
    bf16x8 bfr[4][2];   // [trow-tile][k-half]
#pragma unroll
    for (int tt = 0; tt < 4; ++tt)
#pragma unroll
      for (int kt = 0; kt < 2; ++kt)
        bfr[tt][kt] = *(const bf16x8*)(sFH + (tt * 16 + ri) * 128 + ((kt * 64 + hi * 16) ^ sw));

    f32x4 acc2[4][4];   // [dout-tile][trow-tile]
#pragma unroll
    for (int j = 0; j < 4; ++j)
#pragma unroll
      for (int tt = 0; tt < 4; ++tt) acc2[j][tt] = (f32x4){0.f, 0.f, 0.f, 0.f};

#pragma unroll 1
    for (int q8 = 0; q8 < 8; ++q8) {
      int i8 = r * 8 + q8;
      wait_vm0();   // stage(i8) landed (issued a full eighth ago)
      sbar();       // all waves: stage(i8) in LDS; eighth i8-1 reads done
      if (i8 < 15) STAGE(i8 + 1);   // -> buf((i8+1)&1): free per the barrier

      // ---- Wd frags at PHASE TOP (global; full-phase latency cover) ----
      bf16x8 wdf[4];
#pragma unroll
      for (int j = 0; j < 4; ++j)
        wdf[j] = *(const bf16x8*)(wd + (j * 16 + ri) * 256 + q8 * 32 + hi * 8);

      const char* bufW = sW + (i8 & 1) * 8192;

      // ---- P2: 2 F-tiles x 4 trow-tiles; silu -> h ----
#pragma unroll
      for (int ftl = 0; ftl < 2; ++ftl) {
        const char* bg = bufW + (ftl * 16 + ri) * 128;
        const char* bu = bg + 4096;
        bf16x8 wg0 = *(const bf16x8*)(bg + ((hi * 16) ^ sw));
        bf16x8 wg1 = *(const bf16x8*)(bg + ((64 + hi * 16) ^ sw));
        bf16x8 wu0 = *(const bf16x8*)(bu + ((hi * 16) ^ sw));
        bf16x8 wu1 = *(const bf16x8*)(bu + ((64 + hi * 16) ^ sw));
        f32x4 ag[4], au[4];
#pragma unroll
        for (int tt = 0; tt < 4; ++tt) {
          ag[tt] = (f32x4){0.f, 0.f, 0.f, 0.f};
          au[tt] = (f32x4){0.f, 0.f, 0.f, 0.f};
        }
        __builtin_amdgcn_s_setprio(1);
#pragma unroll
        for (int tt = 0; tt < 4; ++tt) {
          ag[tt] = __builtin_amdgcn_mfma_f32_16x16x32_bf16(wg0, bfr[tt][0], ag[tt], 0, 0, 0);
          au[tt] = __builtin_amdgcn_mfma_f32_16x16x32_bf16(wu0, bfr[tt][0], au[tt], 0, 0, 0);
          ag[tt] = __builtin_amdgcn_mfma_f32_16x16x32_bf16(wg1, bfr[tt][1], ag[tt], 0, 0, 0);
          au[tt] = __builtin_amdgcn_mfma_f32_16x16x32_bf16(wu1, bfr[tt][1], au[tt], 0, 0, 0);
        }
        __builtin_amdgcn_s_setprio(0);
#pragma unroll
        for (int tt = 0; tt < 4; ++tt) {
          float hh[4];
#pragma unroll
          for (int rr = 0; rr < 4; ++rr) {
            float gv = ag[tt][rr], uu = au[tt][rr];
            hh[rr] = gv * uu * frcp(1.f + __expf(-gv));
          }
          uint2 hwv;
          hwv.x = pk2bf(hh[0], hh[1]);
          hwv.y = pk2bf(hh[2], hh[3]);
          // h (F_loc = ftl*16+hi*4+rr, trow = tt*16+ri) -> swizzled
          *(uint2*)(sFH + (tt * 16 + ri) * 128 + ((ftl * 32 + hi * 8) ^ sw)) = hwv;
        }
      }
      wait_lgkm0();  // own h writes complete before hk reads

      // ---- P4: acc2[dout][trow-tile] += Wd x h (one 32-k chunk) ----
      bf16x8 hk[4];
#pragma unroll
      for (int tt = 0; tt < 4; ++tt)
        hk[tt] = *(const bf16x8*)(sFH + (tt * 16 + ri) * 128 + ((hi * 16) ^ sw));
      __builtin_amdgcn_s_setprio(1);
#pragma unroll
      for (int j = 0; j < 4; ++j)
#pragma unroll
        for (int tt = 0; tt < 4; ++tt)
          acc2[j][tt] = __builtin_amdgcn_mfma_f32_16x16x32_bf16(wdf[j], hk[tt], acc2[j][tt], 0, 0, 0);
      __builtin_amdgcn_s_setprio(0);
    }

    // ---- P5: delta transpose through sFH (h dead), then reg residual add ----
    {
#pragma unroll
      for (int tt = 0; tt < 4; ++tt) {
        int tl = tt * 2 + (ri >> 3);
        int kb = ri & 7;
#pragma unroll
        for (int j = 0; j < 4; ++j) {
          uint2 dv;
          dv.x = pk2bf(acc2[j][tt][0], acc2[j][tt][1]);
          dv.y = pk2bf(acc2[j][tt][2], acc2[j][tt][3]);
          *(uint2*)(sFH + tl * 1024 + kb * 128 + ((j * 32 + hi * 8) ^ sw)) = dv;
        }
      }
      wait_lgkm0();
#pragma unroll
      for (int i = 0; i < 8; ++i) {
        uint4 dv = *(const uint4*)(sFH + t8 * 1024 + i * 128 + ((16 * q) ^ (i << 4)));
        unsigned* up = (unsigned*)&uv[i];
        const unsigned* dp = (const unsigned*)&dv;
#pragma unroll
        for (int w = 0; w < 4; ++w) {
          float a0 = bf2f((unsigned short)(up[w] & 0xffff)) +
                     bf2f((unsigned short)(dp[w] & 0xffff));
          float a1 = bf2f((unsigned short)(up[w] >> 16)) +
                     bf2f((unsigned short)(dp[w] >> 16));
          up[w] = pk2bf(a0, a1);
        }
      }
    }
    wait_lgkm0();   // readbacks done before next round's P1b overwrites sFH

    // ---- r1: dump reg residual -> Mvb (linear [token][512]) ----
    if (r == 1) {
      long row = (long)e * 2048 + bx * 32 + wid * 8 + t8;
      unsigned short* dst = Mvb + row * 512 + 8 * q;
#pragma unroll
      for (int i = 0; i < 8; ++i)
        *(uint4*)(dst + i * 64) = uv[i];
    }
  }
}

// ---------- fused out-projection + LayerNorm(D=1024), 512 threads/block ----------
// A (mvb) is LINEAR [token][512] bf16; tiled LDS layout derived via per-lane source addr.
__global__ __launch_bounds__(512, 2) void gemm_out_ln_k(
    const unsigned short* __restrict__ Mvb, const unsigned short* __restrict__ Pw,
    float* __restrict__ Out, const float* __restrict__ ow, const float* __restrict__ ob,
    const int* __restrict__ offs) {
  extern __shared__ char smem[];
  int bid = blockIdx.x;
  int wg = (bid & 7) * 64 + (bid >> 3);
  int e = wg >> 5, mb = wg & 31;
  int tid = threadIdx.x, wid = tid >> 6, lane = tid & 63;
  int ri = lane & 15, hi = lane >> 4;
  long bbase = (long)e * 524288;                 // poutT expert base (tiled)
  long arow0 = (long)e * 2048 + (long)mb * 64;   // mvb expert row base (linear)

  auto STAGE = [&](int buf, int kt) {
#pragma unroll
    for (int i = 0; i < 8; ++i) {
      int q = i * 512 + tid;
      int w = q >> 5, c = (q >> 3) & 3, rr = q & 7;
      async16(Pw + bbase + (long)w * 4096 + (kt * 4 + c) * 64 + rr * 8,
              (unsigned short*)(smem + buf * 65536 + q * 16));
    }
    if (tid < 256) {
      int q = tid;
      int w = q >> 5, c = (q >> 3) & 3, rr = q & 7;
      async16(Mvb + (arow0 + w * 8 + rr) * 512 + kt * 32 + c * 8,
              (unsigned short*)(smem + 131072 + buf * 4096 + q * 16));
    }
  };

  f32x4 acc[4][8];
#pragma unroll
  for (int i = 0; i < 4; ++i)
#pragma unroll
    for (int j = 0; j < 8; ++j) acc[i][j] = (f32x4){0.f, 0.f, 0.f, 0.f};

  STAGE(0, 0);
  for (int kt = 0; kt < 16; ++kt) {
    int cur = kt & 1;
    if (kt < 15) {
      STAGE(cur ^ 1, kt + 1);
      asm volatile("s_waitcnt vmcnt(8)" ::: "memory");
    } else {
      asm volatile("s_waitcnt vmcnt(0)" ::: "memory");
    }
    sbar();
    const char* cB = smem + cur * 65536;
    const char* cA = smem + 131072 + cur * 4096;
    bf16x8 a[4], b[8];
#pragma unroll
    for (int i = 0; i < 4; ++i) a[i] = ld_frag(cA, i * 16 + ri, hi);
#pragma unroll
    for (int j = 0; j < 8; ++j) b[j] = ld_frag(cB, wid * 128 + j * 16 + ri, hi);
    __builtin_amdgcn_s_setprio(1);
#pragma unroll
    for (int i = 0; i < 4; ++i)
#pragma unroll
      for (int j = 0; j < 8; ++j)
        acc[i][j] = __builtin_amdgcn_mfma_f32_16x16x32_bf16(a[i], b[j], acc[i][j], 0, 0, 0);
    __builtin_amdgcn_s_setprio(0);
    sbar();
  }

  float* rsum = (float*)(smem + 139264);
  float* rsq  = (float*)(smem + 141312);
  float* mexp = (float*)(smem + 143360);
  float* rstd = (float*)(smem + 143616);
  int hi4 = hi * 4;
#pragma unroll
  for (int i = 0; i < 4; ++i)
#pragma unroll
    for (int rr = 0; rr < 4; ++rr) {
      float s = 0.f, qv = 0.f;
#pragma unroll
      for (int j = 0; j < 8; ++j) { float v = acc[i][j][rr]; s += v; qv += v * v; }
#pragma unroll
      for (int off = 1; off < 16; off <<= 1) {
        s += __shfl_xor(s, off);
        qv += __shfl_xor(qv, off);
      }
      if (ri == 0) {
        int row = i * 16 + hi4 + rr;
        rsum[row * 8 + wid] = s;
        rsq[row * 8 + wid] = qv;
      }
    }
  __syncthreads();
  if (tid < 64) {
    float S = 0.f, Q = 0.f;
#pragma unroll
    for (int w = 0; w < 8; ++w) { S += rsum[tid * 8 + w]; Q += rsq[tid * 8 + w]; }
    float mean = S * (1.f / 1024.f);
    float var = Q * (1.f / 1024.f) - mean * mean;
    mexp[tid] = mean;
    rstd[tid] = rsqrtf(var + 1e-5f);
  }
  __syncthreads();
  long r0 = (long)offs[e] + (long)mb * 64;
  float owv[8], obv[8];
#pragma unroll
  for (int j = 0; j < 8; ++j) {
    int col = wid * 128 + j * 16 + ri;
    owv[j] = ow[col];
    obv[j] = ob[col];
  }
#pragma unroll
  for (int i = 0; i < 4; ++i)
#pragma unroll
    for (int rr = 0; rr < 4; ++rr) {
      int row = i * 16 + hi4 + rr;
      float mu = mexp[row], rs = rstd[row];
#pragma unroll
      for (int j = 0; j < 8; ++j) {
        int col = wid * 128 + j * 16 + ri;
        Out[(r0 + row) * 1024 + col] = (acc[i][j][rr] - mu) * rs * owv[j] + obv[j];
      }
    }
}

// ---------- host ----------
extern "C" void kernel_launch(void* const* d_in, const int* in_sizes, int n_in,
                              void* d_out, int out_size, void* d_ws, size_t ws_size,
                              hipStream_t stream) {
  const float* x    = (const float*)d_in[0];
  const float* pin  = (const float*)d_in[1];
  const float* pout = (const float*)d_in[2];
  const float* iw   = (const float*)d_in[3];
  const float* gg   = (const float*)d_in[4];
  const float* fg   = (const float*)d_in[5];
  const float* fu   = (const float*)d_in[6];
  const float* fd   = (const float*)d_in[7];
  const float* lnw  = (const float*)d_in[8];
  const float* lnb  = (const float*)d_in[9];
  const float* ow   = (const float*)d_in[10];
  const float* ob   = (const float*)d_in[11];
  const int* offs   = (const int*)d_in[12];

  char* ws = (char*)d_ws;
  unsigned short* mvB  = (unsigned short*)(ws + 0L);          //  33,554,432 B (linear bf16)
  unsigned short* mvb  = (unsigned short*)(ws + 33554432L);   //  33,554,432 B (linear bf16)
  unsigned short* pinT = (unsigned short*)(ws + 67108864L);   //  16,777,216 B (tiled)
  unsigned short* poutT= (unsigned short*)(ws + 83886080L);   //  16,777,216 B (tiled)
  unsigned short* wgT  = (unsigned short*)(ws + 100663296L);  //   2,097,152 B (swz-64)
  unsigned short* wuT  = (unsigned short*)(ws + 102760448L);  //   2,097,152 B (swz-64)
  unsigned short* wdT  = (unsigned short*)(ws + 104857600L);  //   2,097,152 B (plain)
  float* wcomb         = (float*)(ws + 106954752L);           //   5,120 B

  // ALL prep in ONE dispatch
  prep_k<<<dim3(5633), dim3(256), 0, stream>>>(
      pin, pout, fg, fu, fd, iw, gg, pinT, poutT, wgT, wuT, wdT, wcomb);

  // mvB = x @ Pin (A fp32->bf16 reg-staged in-kernel; B from tiled pinT)
  gemm_in_k<<<dim3(256), dim3(512), 131072, stream>>>(x, pinT, mvB, offs);

  // both rounds in ONE kernel; 8 tokens/wave, reg residual, 48K LDS -> 3 blk/CU
  rounds_k<<<dim3(1024), dim3(256), 49152, stream>>>(
      mvB, wgT, wuT, wdT, wcomb, lnw, lnb, mvb);

  // out = LN(mvb @ Pout)
  gemm_out_ln_k<<<dim3(512), dim3(512), 143872, stream>>>(
      mvb, poutT, (float*)d_out, ow, ob, offs);
}

// Round 10
// 313.497 us; speedup vs baseline: 1.0008x; 1.0008x over previous
//
#include <hip/hip_runtime.h>

#define DEV __device__ __forceinline__

typedef __attribute__((ext_vector_type(4))) float f32x4;
typedef __attribute__((ext_vector_type(2))) float f32x2;
typedef __attribute__((ext_vector_type(8))) short bf16x8;

// Shapes: E=16, D=1024, ED=512, NB=8, DB=64, R=2, F=256, N=32768, C=2048

// ---------- helpers ----------
DEV unsigned short f2bf(float f) {
  union { float f; unsigned u; } v; v.f = f;
  unsigned r = v.u + 0x7fffu + ((v.u >> 16) & 1u);
  return (unsigned short)(r >> 16);
}

DEV unsigned pk2bf(float lo, float hi) {  // v_cvt_pk_bf16_f32 (RNE)
  unsigned r;
  asm("v_cvt_pk_bf16_f32 %0, %1, %2" : "=v"(r) : "v"(lo), "v"(hi));
  return r;
}
DEV unsigned short f2bf1(float v) { return (unsigned short)pk2bf(v, v); }

DEV float bf2f(unsigned short b) {
  union { unsigned u; float f; } v; v.u = ((unsigned)b) << 16; return v.f;
}

// packed bf16x2 add in fp32 (SSA-only; no address-taking -> no scratch demotion)
DEV unsigned addbf2(unsigned a, unsigned b) {
  float lo = bf2f((unsigned short)(a & 0xffff)) + bf2f((unsigned short)(b & 0xffff));
  float hi = bf2f((unsigned short)(a >> 16)) + bf2f((unsigned short)(b >> 16));
  return pk2bf(lo, hi);
}

DEV float frcp(float x) { return __builtin_amdgcn_rcpf(x); }

// raw barrier: NO implicit vmcnt drain. "memory" clobber = compiler fence.
DEV void sbar() { asm volatile("s_barrier" ::: "memory"); }
DEV void wait_lgkm0() { asm volatile("s_waitcnt lgkmcnt(0)" ::: "memory"); }
DEV void wait_vm0() { asm volatile("s_waitcnt vmcnt(0)" ::: "memory"); }

DEV void async16(const unsigned short* g, unsigned short* l) {
  __builtin_amdgcn_global_load_lds(
      (__attribute__((address_space(1))) const unsigned int*)g,
      (__attribute__((address_space(3))) unsigned int*)l, 16, 0, 0);
}

// Tiled global layout for GEMM operands: element (n,k) of an [N][K] panel at
//   (n>>3)*8K + (k>>3)*64 + (n&7)*8 + (k&7)
DEV long tiled_off(long n, int k, int K) {
  return (n >> 3) * (8L * K) + (long)(((k >> 3) * 64) + ((int)(n & 7)) * 8 + (k & 7));
}

// frag read from a tiled 32-k LDS subtile (bf16)
DEV bf16x8 ld_frag(const char* s, int row, int hi) {
  return *(const bf16x8*)(s + ((row >> 3) * 512 + hi * 128 + (row & 7) * 16));
}

// ---------- Cayley table at compile time ----------
__host__ __device__ constexpr int km_(int i) { return i==0?0:i==1?1:i==2?2:i==3?4:i==4?3:i==5?5:i==6?6:7; }
__host__ __device__ constexpr int pc_(int x) { int c = 0; while (x) { c += x & 1; x >>= 1; } return c; }
__host__ __device__ constexpr int KIDX(int i, int j) { return km_(km_(i) ^ km_(j)); }
__host__ __device__ constexpr int CSGN(int i, int j) {
  int a = km_(i), b = km_(j), aa = a >> 1, s = 0;
  while (aa) { s += pc_(aa & b); aa >>= 1; }
  return (s & 1) ? -1 : 1;
}
__host__ __device__ constexpr int PIDX(int i, int j) {  // i<=j
  return 8 * i - (i * (i - 1)) / 2 + (j - i);
}

// ---------- prep bodies (merged into ONE dispatch) ----------

DEV void geoprep_body(const float* __restrict__ iw, const float* __restrict__ gg,
                      float* __restrict__ wcomb, int er) {
  const float* w = iw + er * 64;
  float gate = frcp(1.f + __expf(-gg[er]));
  float* c = wcomb + er * 40;
  int p = 0;
  for (int i = 0; i < 8; ++i)
    for (int j = i; j < 8; ++j) {
      float v = (float)CSGN(i, j) * frcp(1.f + __expf(-w[i * 8 + j]));
      if (j > i) v += (float)CSGN(j, i) * frcp(1.f + __expf(-w[j * 8 + i]));
      c[p++] = gate * v;
    }
  c[36] = 1.f - gate;
}

// small transpose: in (Rr,Cc) fp32 (batch bz) -> (Cc,Rr) bf16.
// TI=0 linear; TI=1: k ^= (row&7)<<3 (needs Rr==64).
template<int TI>
DEV void transpose_body(const float* __restrict__ in, unsigned short* __restrict__ out,
                        int Rr, int Cc, int bx, int by, int bz, int tid, char* sbuf) {
  unsigned short (*tile)[33] = (unsigned short (*)[33])sbuf;
  const float* ib = in + (long)bz * Rr * Cc;
  unsigned short* ob = out + (long)bz * Rr * Cc;
  int r0 = by * 32, c0 = bx * 32;
  int tr = tid >> 5, tc = tid & 31;
#pragma unroll
  for (int i = 0; i < 4; ++i) {
    int r = tr + i * 8;
    tile[r][tc] = f2bf(ib[(long)(r0 + r) * Cc + c0 + tc]);
  }
  __syncthreads();
#pragma unroll
  for (int i = 0; i < 4; ++i) {
    int c = tr + i * 8;
    int row = c0 + c;
    int k = r0 + tc;
    if (TI == 0) ob[(long)row * Rr + k] = tile[tc][c];
    else ob[(long)row * Rr + (k ^ ((row & 7) << 3))] = tile[tc][c];
  }
}

// big convert+transpose for pin/pout: in [Rr k][Cc n] fp32 -> out tiled bf16 [n][k].
DEV void trans_big_body(const float* __restrict__ in, unsigned short* __restrict__ out,
                        int Rr, int Cc, int bx, int by, int bz, int tid, char* sbuf) {
  float (*t)[64] = (float (*)[64])sbuf;
  const float* ib = in + (long)bz * Rr * Cc;
  unsigned short* ob = out + (long)bz * (long)Rr * Cc;
  int k0 = by * 64, n0 = bx * 64;
#pragma unroll
  for (int p = 0; p < 4; ++p) {
    int idx = p * 256 + tid;
    int kr = idx >> 4, nc = (idx & 15) * 4;
    *(float4*)&t[kr][nc] = *(const float4*)(ib + (long)(k0 + kr) * Cc + n0 + nc);
  }
  __syncthreads();
#pragma unroll
  for (int p = 0; p < 2; ++p) {
    int idx = p * 256 + tid;
    int n = idx & 63, kc = idx >> 6;       // kc 0..7
    float v[8];
#pragma unroll
    for (int u = 0; u < 8; ++u) v[u] = t[kc * 8 + u][n];
    uint4 o;
    o.x = pk2bf(v[0], v[1]); o.y = pk2bf(v[2], v[3]);
    o.z = pk2bf(v[4], v[5]); o.w = pk2bf(v[6], v[7]);
    *(uint4*)(ob + tiled_off(n0 + n, k0 + kc * 8, Rr)) = o;
  }
}

// ONE dispatch for all prep: blocks 0..2047 pinT, 2048..4095 poutT,
// 4096..4607 wgT, 4608..5119 wuT, 5120..5631 wdT, 5632 geoprep.
__global__ __launch_bounds__(256) void prep_k(
    const float* __restrict__ pin, const float* __restrict__ pout,
    const float* __restrict__ fg, const float* __restrict__ fu,
    const float* __restrict__ fd, const float* __restrict__ iw,
    const float* __restrict__ gg,
    unsigned short* __restrict__ pinT, unsigned short* __restrict__ poutT,
    unsigned short* __restrict__ wgT, unsigned short* __restrict__ wuT,
    unsigned short* __restrict__ wdT, float* __restrict__ wcomb) {
  __shared__ char sbuf[16384];
  int b = blockIdx.x, tid = threadIdx.x;
  if (b < 2048) {
    trans_big_body(pin, pinT, 1024, 512, b & 7, (b >> 3) & 15, b >> 7, tid, sbuf);
  } else if (b < 4096) {
    int j = b - 2048;
    trans_big_body(pout, poutT, 512, 1024, j & 15, (j >> 4) & 7, j >> 7, tid, sbuf);
  } else if (b < 4608) {
    int j = b - 4096;
    transpose_body<1>(fg, wgT, 64, 256, j & 7, (j >> 3) & 1, j >> 4, tid, sbuf);
  } else if (b < 5120) {
    int j = b - 4608;
    transpose_body<1>(fu, wuT, 64, 256, j & 7, (j >> 3) & 1, j >> 4, tid, sbuf);
  } else if (b < 5632) {
    int j = b - 5120;
    transpose_body<0>(fd, wdT, 256, 64, j & 1, (j >> 1) & 7, j >> 4, tid, sbuf);
  } else {
    if (tid < 32) geoprep_body(iw, gg, wcomb, tid);
  }
}

// GEMM1 (convert FUSED): mvB(bf16, linear [token][512]) = x @ Pin^T per expert.
// 256x256 tile, BK=64 in two 32-sub-phases. B staged via async16 from tiled
// pinT; A staged from x fp32 directly (reg-load -> cvt -> ds_write, T14 split).
__global__ __launch_bounds__(512, 1) void gemm_in_k(const float* __restrict__ X,
                                                    const unsigned short* __restrict__ Bw,
                                                    unsigned short* __restrict__ MvB,
                                                    const int* __restrict__ offs) {
  extern __shared__ char smem[];    // [2 buf][ A 32K | B 32K ], each op as 2 x 16K ksub
  int bid = blockIdx.x;             // 256 blocks
  int wg = (bid & 7) * 32 + (bid >> 3);      // XCD swizzle (256 % 8 == 0)
  int e = wg >> 4, rem = wg & 15, bm = rem >> 1, bn = rem & 1;
  int tid = threadIdx.x, wid = tid >> 6, lane = tid & 63;
  int wm = (wid >> 2) * 128, wn = (wid & 3) * 64;
  int ri = lane & 15, hi = lane >> 4;
  long rowbase = (long)offs[e] + bm * 256;   // A row base (x fp32 linear)
  long bw = (long)e * 64 + bn * 32;          // B window base (pinT tiled, K=1024)

  // phase p = t*2+s (t=K-tile 0..15, s=32-k sub 0..1)
  auto STGB = [&](int p) {
    int t = p >> 1, s = p & 1, b = t & 1;
    char* dst = smem + b * 65536 + 32768 + s * 16384;
#pragma unroll
    for (int i = 0; i < 2; ++i) {
      int d = i * 512 + tid;
      async16(Bw + (bw + (d >> 5)) * 8192 +
                  (long)((t * 8 + s * 4 + ((d >> 3) & 3)) * 64 + (d & 7) * 8),
              (unsigned short*)(dst + d * 16));
    }
  };
  auto A_LOAD = [&](int p, float4 ar[2][2]) {
    int t = p >> 1, s = p & 1;
#pragma unroll
    for (int i = 0; i < 2; ++i) {
      int d = i * 512 + tid;
      const float* src = X + (rowbase + ((d >> 5) * 8 + (d & 7))) * 1024 +
                         t * 64 + s * 32 + ((d >> 3) & 3) * 8;
      ar[i][0] = *(const float4*)src;
      ar[i][1] = *(const float4*)(src + 4);
    }
  };
  auto A_WRITE = [&](int p, float4 ar[2][2]) {
    int t = p >> 1, s = p & 1, b = t & 1;
    char* dst = smem + b * 65536 + s * 16384;
#pragma unroll
    for (int i = 0; i < 2; ++i) {
      int d = i * 512 + tid;
      uint4 o;
      o.x = pk2bf(ar[i][0].x, ar[i][0].y);
      o.y = pk2bf(ar[i][0].z, ar[i][0].w);
      o.z = pk2bf(ar[i][1].x, ar[i][1].y);
      o.w = pk2bf(ar[i][1].z, ar[i][1].w);
      *(uint4*)(dst + d * 16) = o;
    }
  };

  f32x4 acc[8][4];
#pragma unroll
  for (int i = 0; i < 8; ++i)
#pragma unroll
    for (int j = 0; j < 4; ++j) acc[i][j] = (f32x4){0.f, 0.f, 0.f, 0.f};

  // prologue: phases 0 and 1 staged (A via regs, B via async16)
  float4 ar[2][2];
  A_LOAD(0, ar); STGB(0); STGB(1);
  A_WRITE(0, ar);                 // compiler auto-waits the A regs
  A_LOAD(1, ar);
  A_WRITE(1, ar);
  wait_lgkm0();

#pragma unroll 2
  for (int p = 0; p < 32; ++p) {
    int t = p >> 1, s = p & 1, c = t & 1;
    if (p < 30) { A_LOAD(p + 2, ar); STGB(p + 2); }
    if (p < 30) asm volatile("s_waitcnt vmcnt(8)" ::: "memory");
    else if (p == 30) asm volatile("s_waitcnt vmcnt(2)" ::: "memory");
    else asm volatile("s_waitcnt vmcnt(0)" ::: "memory");
    sbar();
    const char* cA = smem + c * 65536 + s * 16384;
    const char* cB = smem + c * 65536 + 32768 + s * 16384;
    bf16x8 a[8], b[4];
#pragma unroll
    for (int i = 0; i < 8; ++i) a[i] = ld_frag(cA, wm + i * 16 + ri, hi);
#pragma unroll
    for (int j = 0; j < 4; ++j) b[j] = ld_frag(cB, wn + j * 16 + ri, hi);
    __builtin_amdgcn_s_setprio(1);
#pragma unroll
    for (int i = 0; i < 8; ++i)
#pragma unroll
      for (int j = 0; j < 4; ++j)
        acc[i][j] = __builtin_amdgcn_mfma_f32_16x16x32_bf16(a[i], b[j], acc[i][j], 0, 0, 0);
    __builtin_amdgcn_s_setprio(0);
    if (p < 30) A_WRITE(p + 2, ar);
    wait_lgkm0();
  }

  unsigned short* Cb = MvB + ((long)e * 2048 + (long)bm * 256) * 512 + bn * 256;
#pragma unroll
  for (int i = 0; i < 8; ++i)
#pragma unroll
    for (int j = 0; j < 4; ++j)
#pragma unroll
      for (int rr = 0; rr < 4; ++rr)
        Cb[(long)(wm + i * 16 + hi * 4 + rr) * 512 + wn + j * 16 + ri] =
            f2bf1(acc[i][j][rr]);
}

// ---------- merged 2-round fused kernel: 8 TOKENS PER WAVE, REG RESIDUAL ----------
// 32 tokens/block, 256 threads = 4 waves; each wave owns 8 tokens (64 trows,
// 4 trow-tiles) END-TO-END. Residual state lives in 32 VGPRs (uint4 uv[8],
// bf16-packed) -- r9's version of this spilled ~250MB because P5 took
// ADDRESSES into uv ((unsigned*)&uv[i]) which defeats SROA (rule-#20 analog;
// VGPR_Count dropped to 84 = uv demoted to scratch). This version uses pure
// SSA component access (uv[i].x = addbf2(...)) with fully-unrolled constant
// indices -> uv stays in registers.
// P5 frag->token transpose goes through sFH (DEAD at P5: last h consumed by
// final P4): write bf16 deltas, lgkm, read back in (t8,q) layout, add in regs.
// LDS 48K -> 3 blocks/CU (144K) at __launch_bounds__(256,3): VGPR cap 170,
// demand ~140, no spill.
//   sFH  @0     32K: 4 waves x 8K [64 row][128B] xor swz (flat -> h -> P5 scr)
//   sW   @32K   16K: dbuf x (Wg 4K | Wu 4K) eighth (swizzle baked in global)
__global__ __launch_bounds__(256, 3) void rounds_k(
    const unsigned short* __restrict__ MvB, const unsigned short* __restrict__ WgT,
    const unsigned short* __restrict__ WuT, const unsigned short* __restrict__ WdT,
    const float* __restrict__ wcomb, const float* __restrict__ lnw,
    const float* __restrict__ lnb, unsigned short* __restrict__ Mvb) {
  extern __shared__ char smem[];
  int tid = threadIdx.x, wid = tid >> 6, lane = tid & 63;
  char* sFH = smem + wid * 8192;            // wave-private [64 row][128B]
  char* sW  = smem + 32768;                 // dbuf 2 x 8K (Wg 4K | Wu 4K)

  int bid = blockIdx.x;
  int wg = (bid & 7) * 128 + (bid >> 3);    // XCD swizzle (1024 % 8 == 0)
  int e = wg >> 6, bx = wg & 63;

  int t8 = lane >> 3, q = lane & 7;         // P1/P5 coords: token-in-wave, d-octet
  int ri = lane & 15, hi = lane >> 4;       // frag coords
  int sw = (ri & 7) << 4;

  // stage global eighth i8 (0..15; round = i8>>3, slice = i8&7)
  auto STAGE = [&](int i8) {
    long base = (long)(e * 2 + (i8 >> 3)) * 16384 + (i8 & 7) * 2048;
    char* dst = sW + (i8 & 1) * 8192;
    async16(WgT + base + tid * 8, (unsigned short*)(dst + tid * 16));
    async16(WuT + base + tid * 8, (unsigned short*)(dst + 4096 + tid * 16));
  };
  STAGE(0);   // prologue: lands under P1 of round 0

  // ---- persistent residual state in regs: uv[i] = (token t8, blade i, d 8q..8q+7) ----
  uint4 uv[8];
  {
    long base = ((long)e * 2048 + bx * 32 + wid * 8 + t8) * 512 + 8 * q;
#pragma unroll
    for (int i = 0; i < 8; ++i)
      uv[i] = *(const uint4*)(MvB + base + i * 64);
  }

#pragma unroll 1
  for (int r = 0; r < 2; ++r) {
    int er = e * 2 + r;
    const unsigned short* wd = WdT + (long)er * 16384;  // [64 dout][256 F]

    // ---- P1a: unpack reg-resident mv (two f32x4 halves per blade) ----
    f32x4 mv[2][8];
#pragma unroll
    for (int i = 0; i < 8; ++i) {
      mv[0][i] = (f32x4){bf2f((unsigned short)(uv[i].x & 0xffff)),
                         bf2f((unsigned short)(uv[i].x >> 16)),
                         bf2f((unsigned short)(uv[i].y & 0xffff)),
                         bf2f((unsigned short)(uv[i].y >> 16))};
      mv[1][i] = (f32x4){bf2f((unsigned short)(uv[i].z & 0xffff)),
                         bf2f((unsigned short)(uv[i].z >> 16)),
                         bf2f((unsigned short)(uv[i].w & 0xffff)),
                         bf2f((unsigned short)(uv[i].w >> 16))};
    }

    // ---- P1b: geo + mix + LN(64) -> sFH (packed math; wave-private) ----
    {
      const float* C = wcomb + er * 40;
      f32x4 g[2][8];
#pragma unroll
      for (int hf = 0; hf < 2; ++hf)
#pragma unroll
        for (int k = 0; k < 8; ++k) g[hf][k] = (f32x4){0.f, 0.f, 0.f, 0.f};
#pragma unroll
      for (int i = 0; i < 8; ++i)
#pragma unroll
        for (int j = i; j < 8; ++j) {
          float cc = C[PIDX(i, j)];
          const int k = KIDX(i, j);
          g[0][k] += cc * (mv[0][i] * mv[0][j]);
          g[1][k] += cc * (mv[1][i] * mv[1][j]);
        }
      float omg = C[36];
#pragma unroll
      for (int hf = 0; hf < 2; ++hf)
#pragma unroll
        for (int k = 0; k < 8; ++k) g[hf][k] = omg * mv[hf][k] + g[hf][k];
      float4 lwa = *(const float4*)(lnw + (long)er * 64 + 8 * q);
      float4 lwb = *(const float4*)(lnw + (long)er * 64 + 8 * q + 4);
      float4 lba = *(const float4*)(lnb + (long)er * 64 + 8 * q);
      float4 lbb = *(const float4*)(lnb + (long)er * 64 + 8 * q + 4);
      f32x4 lwvA = (f32x4){lwa.x, lwa.y, lwa.z, lwa.w};
      f32x4 lwvB = (f32x4){lwb.x, lwb.y, lwb.z, lwb.w};
      f32x4 lbvA = (f32x4){lba.x, lba.y, lba.z, lba.w};
      f32x4 lbvB = (f32x4){lbb.x, lbb.y, lbb.z, lbb.w};
#pragma unroll
      for (int bh = 0; bh < 2; ++bh) {
        f32x2 red[4];
#pragma unroll
        for (int k = 0; k < 4; ++k) {
          f32x4 a = g[0][bh * 4 + k], b = g[1][bh * 4 + k];
          red[k].x = ((a.x + a.y) + (a.z + a.w)) + ((b.x + b.y) + (b.z + b.w));
          red[k].y = (fmaf(a.x, a.x, a.y * a.y) + fmaf(a.z, a.z, a.w * a.w)) +
                     (fmaf(b.x, b.x, b.y * b.y) + fmaf(b.z, b.z, b.w * b.w));
        }
#pragma unroll
        for (int off = 4; off >= 1; off >>= 1)
#pragma unroll
          for (int t = 0; t < 4; ++t) {
            f32x2 o;
            o.x = __shfl_xor(red[t].x, off);
            o.y = __shfl_xor(red[t].y, off);
            red[t] += o;
          }
#pragma unroll
        for (int k = 0; k < 4; ++k) {
          int kk = bh * 4 + k;
          float mean = red[k].x * (1.f / 64.f);
          float var = red[k].y * (1.f / 64.f) - mean * mean;
          float rs = rsqrtf(var + 1e-5f);
          f32x4 ovA = ((g[0][kk] - mean) * rs) * lwvA + lbvA;
          f32x4 ovB = ((g[1][kk] - mean) * rs) * lwvB + lbvB;
          uint4 pv;
          pv.x = pk2bf(ovA.x, ovA.y);
          pv.y = pk2bf(ovA.z, ovA.w);
          pv.z = pk2bf(ovB.x, ovB.y);
          pv.w = pk2bf(ovB.z, ovB.w);
          int row = t8 * 8 + kk;                    // row&7 == kk
          *(uint4*)(sFH + row * 128 + ((16 * q) ^ (kk << 4))) = pv;
        }
      }
    }
    wait_lgkm0();   // own-wave flat writes done (cross-LANE reads next)

    // ---- hoist flat B-frags to regs (sFH gets reused for h afterwards) ----
    bf16x8 bfr[4][2];   // [trow-tile][k-half]
#pragma unroll
    for (int tt = 0; tt < 4; ++tt)
#pragma unroll
      for (int kt = 0; kt < 2; ++kt)
        bfr[tt][kt] = *(const bf16x8*)(sFH + (tt * 16 + ri) * 128 + ((kt * 64 + hi * 16) ^ sw));

    f32x4 acc2[4][4];   // [dout-tile][trow-tile]
#pragma unroll
    for (int j = 0; j < 4; ++j)
#pragma unroll
      for (int tt = 0; tt < 4; ++tt) acc2[j][tt] = (f32x4){0.f, 0.f, 0.f, 0.f};

#pragma unroll 1
    for (int q8 = 0; q8 < 8; ++q8) {
      int i8 = r * 8 + q8;
      wait_vm0();   // stage(i8) landed (issued a full eighth ago)
      sbar();       // all waves: stage(i8) in LDS; eighth i8-1 reads done
      if (i8 < 15) STAGE(i8 + 1);   // -> buf((i8+1)&1): free per the barrier

      // ---- Wd frags at PHASE TOP (global; full-phase latency cover) ----
      bf16x8 wdf[4];
#pragma unroll
      for (int j = 0; j < 4; ++j)
        wdf[j] = *(const bf16x8*)(wd + (j * 16 + ri) * 256 + q8 * 32 + hi * 8);

      const char* bufW = sW + (i8 & 1) * 8192;

      // ---- P2: 2 F-tiles x 4 trow-tiles; silu -> h ----
#pragma unroll
      for (int ftl = 0; ftl < 2; ++ftl) {
        const char* bg = bufW + (ftl * 16 + ri) * 128;
        const char* bu = bg + 4096;
        bf16x8 wg0 = *(const bf16x8*)(bg + ((hi * 16) ^ sw));
        bf16x8 wg1 = *(const bf16x8*)(bg + ((64 + hi * 16) ^ sw));
        bf16x8 wu0 = *(const bf16x8*)(bu + ((hi * 16) ^ sw));
        bf16x8 wu1 = *(const bf16x8*)(bu + ((64 + hi * 16) ^ sw));
        f32x4 ag[4], au[4];
#pragma unroll
        for (int tt = 0; tt < 4; ++tt) {
          ag[tt] = (f32x4){0.f, 0.f, 0.f, 0.f};
          au[tt] = (f32x4){0.f, 0.f, 0.f, 0.f};
        }
        __builtin_amdgcn_s_setprio(1);
#pragma unroll
        for (int tt = 0; tt < 4; ++tt) {
          ag[tt] = __builtin_amdgcn_mfma_f32_16x16x32_bf16(wg0, bfr[tt][0], ag[tt], 0, 0, 0);
          au[tt] = __builtin_amdgcn_mfma_f32_16x16x32_bf16(wu0, bfr[tt][0], au[tt], 0, 0, 0);
          ag[tt] = __builtin_amdgcn_mfma_f32_16x16x32_bf16(wg1, bfr[tt][1], ag[tt], 0, 0, 0);
          au[tt] = __builtin_amdgcn_mfma_f32_16x16x32_bf16(wu1, bfr[tt][1], au[tt], 0, 0, 0);
        }
        __builtin_amdgcn_s_setprio(0);
#pragma unroll
        for (int tt = 0; tt < 4; ++tt) {
          float hh[4];
#pragma unroll
          for (int rr = 0; rr < 4; ++rr) {
            float gv = ag[tt][rr], uu = au[tt][rr];
            hh[rr] = gv * uu * frcp(1.f + __expf(-gv));
          }
          uint2 hwv;
          hwv.x = pk2bf(hh[0], hh[1]);
          hwv.y = pk2bf(hh[2], hh[3]);
          // h (F_loc = ftl*16+hi*4+rr, trow = tt*16+ri) -> swizzled
          *(uint2*)(sFH + (tt * 16 + ri) * 128 + ((ftl * 32 + hi * 8) ^ sw)) = hwv;
        }
      }
      wait_lgkm0();  // own h writes complete before hk reads

      // ---- P4: acc2[dout][trow-tile] += Wd x h (one 32-k chunk) ----
      bf16x8 hk[4];
#pragma unroll
      for (int tt = 0; tt < 4; ++tt)
        hk[tt] = *(const bf16x8*)(sFH + (tt * 16 + ri) * 128 + ((hi * 16) ^ sw));
      __builtin_amdgcn_s_setprio(1);
#pragma unroll
      for (int j = 0; j < 4; ++j)
#pragma unroll
        for (int tt = 0; tt < 4; ++tt)
          acc2[j][tt] = __builtin_amdgcn_mfma_f32_16x16x32_bf16(wdf[j], hk[tt], acc2[j][tt], 0, 0, 0);
      __builtin_amdgcn_s_setprio(0);
    }

    // ---- P5: delta transpose through sFH (h dead), then SSA reg residual add ----
    {
#pragma unroll
      for (int tt = 0; tt < 4; ++tt) {
        int tl = tt * 2 + (ri >> 3);
        int kb = ri & 7;
#pragma unroll
        for (int j = 0; j < 4; ++j) {
          uint2 dv;
          dv.x = pk2bf(acc2[j][tt][0], acc2[j][tt][1]);
          dv.y = pk2bf(acc2[j][tt][2], acc2[j][tt][3]);
          *(uint2*)(sFH + tl * 1024 + kb * 128 + ((j * 32 + hi * 8) ^ sw)) = dv;
        }
      }
      wait_lgkm0();
#pragma unroll
      for (int i = 0; i < 8; ++i) {
        uint4 dv = *(const uint4*)(sFH + t8 * 1024 + i * 128 + ((16 * q) ^ (i << 4)));
        uv[i].x = addbf2(uv[i].x, dv.x);
        uv[i].y = addbf2(uv[i].y, dv.y);
        uv[i].z = addbf2(uv[i].z, dv.z);
        uv[i].w = addbf2(uv[i].w, dv.w);
      }
    }
    wait_lgkm0();   // readbacks done before next round's P1b overwrites sFH

    // ---- r1: dump reg residual -> Mvb (linear [token][512]) ----
    if (r == 1) {
      long row = (long)e * 2048 + bx * 32 + wid * 8 + t8;
      unsigned short* dst = Mvb + row * 512 + 8 * q;
#pragma unroll
      for (int i = 0; i < 8; ++i)
        *(uint4*)(dst + i * 64) = uv[i];
    }
  }
}

// ---------- fused out-projection + LayerNorm(D=1024), 512 threads/block ----------
// A (mvb) is LINEAR [token][512] bf16; tiled LDS layout derived via per-lane source addr.
__global__ __launch_bounds__(512, 2) void gemm_out_ln_k(
    const unsigned short* __restrict__ Mvb, const unsigned short* __restrict__ Pw,
    float* __restrict__ Out, const float* __restrict__ ow, const float* __restrict__ ob,
    const int* __restrict__ offs) {
  extern __shared__ char smem[];
  int bid = blockIdx.x;
  int wg = (bid & 7) * 64 + (bid >> 3);
  int e = wg >> 5, mb = wg & 31;
  int tid = threadIdx.x, wid = tid >> 6, lane = tid & 63;
  int ri = lane & 15, hi = lane >> 4;
  long bbase = (long)e * 524288;                 // poutT expert base (tiled)
  long arow0 = (long)e * 2048 + (long)mb * 64;   // mvb expert row base (linear)

  auto STAGE = [&](int buf, int kt) {
#pragma unroll
    for (int i = 0; i < 8; ++i) {
      int q = i * 512 + tid;
      int w = q >> 5, c = (q >> 3) & 3, rr = q & 7;
      async16(Pw + bbase + (long)w * 4096 + (kt * 4 + c) * 64 + rr * 8,
              (unsigned short*)(smem + buf * 65536 + q * 16));
    }
    if (tid < 256) {
      int q = tid;
      int w = q >> 5, c = (q >> 3) & 3, rr = q & 7;
      async16(Mvb + (arow0 + w * 8 + rr) * 512 + kt * 32 + c * 8,
              (unsigned short*)(smem + 131072 + buf * 4096 + q * 16));
    }
  };

  f32x4 acc[4][8];
#pragma unroll
  for (int i = 0; i < 4; ++i)
#pragma unroll
    for (int j = 0; j < 8; ++j) acc[i][j] = (f32x4){0.f, 0.f, 0.f, 0.f};

  STAGE(0, 0);
  for (int kt = 0; kt < 16; ++kt) {
    int cur = kt & 1;
    if (kt < 15) {
      STAGE(cur ^ 1, kt + 1);
      asm volatile("s_waitcnt vmcnt(8)" ::: "memory");
    } else {
      asm volatile("s_waitcnt vmcnt(0)" ::: "memory");
    }
    sbar();
    const char* cB = smem + cur * 65536;
    const char* cA = smem + 131072 + cur * 4096;
    bf16x8 a[4], b[8];
#pragma unroll
    for (int i = 0; i < 4; ++i) a[i] = ld_frag(cA, i * 16 + ri, hi);
#pragma unroll
    for (int j = 0; j < 8; ++j) b[j] = ld_frag(cB, wid * 128 + j * 16 + ri, hi);
    __builtin_amdgcn_s_setprio(1);
#pragma unroll
    for (int i = 0; i < 4; ++i)
#pragma unroll
      for (int j = 0; j < 8; ++j)
        acc[i][j] = __builtin_amdgcn_mfma_f32_16x16x32_bf16(a[i], b[j], acc[i][j], 0, 0, 0);
    __builtin_amdgcn_s_setprio(0);
    sbar();
  }

  float* rsum = (float*)(smem + 139264);
  float* rsq  = (float*)(smem + 141312);
  float* mexp = (float*)(smem + 143360);
  float* rstd = (float*)(smem + 143616);
  int hi4 = hi * 4;
#pragma unroll
  for (int i = 0; i < 4; ++i)
#pragma unroll
    for (int rr = 0; rr < 4; ++rr) {
      float s = 0.f, qv = 0.f;
#pragma unroll
      for (int j = 0; j < 8; ++j) { float v = acc[i][j][rr]; s += v; qv += v * v; }
#pragma unroll
      for (int off = 1; off < 16; off <<= 1) {
        s += __shfl_xor(s, off);
        qv += __shfl_xor(qv, off);
      }
      if (ri == 0) {
        int row = i * 16 + hi4 + rr;
        rsum[row * 8 + wid] = s;
        rsq[row * 8 + wid] = qv;
      }
    }
  __syncthreads();
  if (tid < 64) {
    float S = 0.f, Q = 0.f;
#pragma unroll
    for (int w = 0; w < 8; ++w) { S += rsum[tid * 8 + w]; Q += rsq[tid * 8 + w]; }
    float mean = S * (1.f / 1024.f);
    float var = Q * (1.f / 1024.f) - mean * mean;
    mexp[tid] = mean;
    rstd[tid] = rsqrtf(var + 1e-5f);
  }
  __syncthreads();
  long r0 = (long)offs[e] + (long)mb * 64;
  float owv[8], obv[8];
#pragma unroll
  for (int j = 0; j < 8; ++j) {
    int col = wid * 128 + j * 16 + ri;
    owv[j] = ow[col];
    obv[j] = ob[col];
  }
#pragma unroll
  for (int i = 0; i < 4; ++i)
#pragma unroll
    for (int rr = 0; rr < 4; ++rr) {
      int row = i * 16 + hi4 + rr;
      float mu = mexp[row], rs = rstd[row];
#pragma unroll
      for (int j = 0; j < 8; ++j) {
        int col = wid * 128 + j * 16 + ri;
        Out[(r0 + row) * 1024 + col] = (acc[i][j][rr] - mu) * rs * owv[j] + obv[j];
      }
    }
}

// ---------- host ----------
extern "C" void kernel_launch(void* const* d_in, const int* in_sizes, int n_in,
                              void* d_out, int out_size, void* d_ws, size_t ws_size,
                              hipStream_t stream) {
  const float* x    = (const float*)d_in[0];
  const float* pin  = (const float*)d_in[1];
  const float* pout = (const float*)d_in[2];
  const float* iw   = (const float*)d_in[3];
  const float* gg   = (const float*)d_in[4];
  const float* fg   = (const float*)d_in[5];
  const float* fu   = (const float*)d_in[6];
  const float* fd   = (const float*)d_in[7];
  const float* lnw  = (const float*)d_in[8];
  const float* lnb  = (const float*)d_in[9];
  const float* ow   = (const float*)d_in[10];
  const float* ob   = (const float*)d_in[11];
  const int* offs   = (const int*)d_in[12];

  char* ws = (char*)d_ws;
  unsigned short* mvB  = (unsigned short*)(ws + 0L);          //  33,554,432 B (linear bf16)
  unsigned short* mvb  = (unsigned short*)(ws + 33554432L);   //  33,554,432 B (linear bf16)
  unsigned short* pinT = (unsigned short*)(ws + 67108864L);   //  16,777,216 B (tiled)
  unsigned short* poutT= (unsigned short*)(ws + 83886080L);   //  16,777,216 B (tiled)
  unsigned short* wgT  = (unsigned short*)(ws + 100663296L);  //   2,097,152 B (swz-64)
  unsigned short* wuT  = (unsigned short*)(ws + 102760448L);  //   2,097,152 B (swz-64)
  unsigned short* wdT  = (unsigned short*)(ws + 104857600L);  //   2,097,152 B (plain)
  float* wcomb         = (float*)(ws + 106954752L);           //   5,120 B

  // ALL prep in ONE dispatch
  prep_k<<<dim3(5633), dim3(256), 0, stream>>>(
      pin, pout, fg, fu, fd, iw, gg, pinT, poutT, wgT, wuT, wdT, wcomb);

  // mvB = x @ Pin (A fp32->bf16 reg-staged in-kernel; B from tiled pinT)
  gemm_in_k<<<dim3(256), dim3(512), 131072, stream>>>(x, pinT, mvB, offs);

  // both rounds in ONE kernel; 8 tokens/wave, reg residual (SSA), 48K LDS
  rounds_k<<<dim3(1024), dim3(256), 49152, stream>>>(
      mvB, wgT, wuT, wdT, wcomb, lnw, lnb, mvb);

  // out = LN(mvb @ Pout)
  gemm_out_ln_k<<<dim3(512), dim3(512), 143872, stream>>>(
      mvb, poutT, (float*)d_out, ow, ob, offs);
}

// Round 11
// 260.225 us; speedup vs baseline: 1.2057x; 1.2047x over previous
//
#include <hip/hip_runtime.h>

#define DEV __device__ __forceinline__

typedef __attribute__((ext_vector_type(4))) float f32x4;
typedef __attribute__((ext_vector_type(2))) float f32x2;
typedef __attribute__((ext_vector_type(8))) short bf16x8;

// Shapes: E=16, D=1024, ED=512, NB=8, DB=64, R=2, F=256, N=32768, C=2048

// ---------- helpers ----------
DEV unsigned short f2bf(float f) {
  union { float f; unsigned u; } v; v.f = f;
  unsigned r = v.u + 0x7fffu + ((v.u >> 16) & 1u);
  return (unsigned short)(r >> 16);
}

DEV unsigned pk2bf(float lo, float hi) {  // v_cvt_pk_bf16_f32 (RNE)
  unsigned r;
  asm("v_cvt_pk_bf16_f32 %0, %1, %2" : "=v"(r) : "v"(lo), "v"(hi));
  return r;
}
DEV unsigned short f2bf1(float v) { return (unsigned short)pk2bf(v, v); }

DEV float bf2f(unsigned short b) {
  union { unsigned u; float f; } v; v.u = ((unsigned)b) << 16; return v.f;
}

// packed bf16x2 add in fp32 (SSA-only)
DEV unsigned addbf2(unsigned a, unsigned b) {
  float lo = bf2f((unsigned short)(a & 0xffff)) + bf2f((unsigned short)(b & 0xffff));
  float hi = bf2f((unsigned short)(a >> 16)) + bf2f((unsigned short)(b >> 16));
  return pk2bf(lo, hi);
}

DEV float frcp(float x) { return __builtin_amdgcn_rcpf(x); }

// raw barrier: NO implicit vmcnt drain. "memory" clobber = compiler fence.
DEV void sbar() { asm volatile("s_barrier" ::: "memory"); }
DEV void wait_lgkm0() { asm volatile("s_waitcnt lgkmcnt(0)" ::: "memory"); }
DEV void wait_vm0() { asm volatile("s_waitcnt vmcnt(0)" ::: "memory"); }

DEV void async16(const unsigned short* g, unsigned short* l) {
  __builtin_amdgcn_global_load_lds(
      (__attribute__((address_space(1))) const unsigned int*)g,
      (__attribute__((address_space(3))) unsigned int*)l, 16, 0, 0);
}

// Tiled global layout for GEMM operands: element (n,k) of an [N][K] panel at
//   (n>>3)*8K + (k>>3)*64 + (n&7)*8 + (k&7)
DEV long tiled_off(long n, int k, int K) {
  return (n >> 3) * (8L * K) + (long)(((k >> 3) * 64) + ((int)(n & 7)) * 8 + (k & 7));
}

// frag read from a tiled 32-k LDS subtile (bf16)
DEV bf16x8 ld_frag(const char* s, int row, int hi) {
  return *(const bf16x8*)(s + ((row >> 3) * 512 + hi * 128 + (row & 7) * 16));
}

// ---------- Cayley table at compile time ----------
__host__ __device__ constexpr int km_(int i) { return i==0?0:i==1?1:i==2?2:i==3?4:i==4?3:i==5?5:i==6?6:7; }
__host__ __device__ constexpr int pc_(int x) { int c = 0; while (x) { c += x & 1; x >>= 1; } return c; }
__host__ __device__ constexpr int KIDX(int i, int j) { return km_(km_(i) ^ km_(j)); }
__host__ __device__ constexpr int CSGN(int i, int j) {
  int a = km_(i), b = km_(j), aa = a >> 1, s = 0;
  while (aa) { s += pc_(aa & b); aa >>= 1; }
  return (s & 1) ? -1 : 1;
}
__host__ __device__ constexpr int PIDX(int i, int j) {  // i<=j
  return 8 * i - (i * (i - 1)) / 2 + (j - i);
}

// ---------- prep bodies (merged into ONE dispatch) ----------

DEV void geoprep_body(const float* __restrict__ iw, const float* __restrict__ gg,
                      float* __restrict__ wcomb, int er) {
  const float* w = iw + er * 64;
  float gate = frcp(1.f + __expf(-gg[er]));
  float* c = wcomb + er * 40;
  int p = 0;
  for (int i = 0; i < 8; ++i)
    for (int j = i; j < 8; ++j) {
      float v = (float)CSGN(i, j) * frcp(1.f + __expf(-w[i * 8 + j]));
      if (j > i) v += (float)CSGN(j, i) * frcp(1.f + __expf(-w[j * 8 + i]));
      c[p++] = gate * v;
    }
  c[36] = 1.f - gate;
}

// small transpose: in (Rr,Cc) fp32 (batch bz) -> (Cc,Rr) bf16.
// TI=0 linear; TI=1: k ^= (row&7)<<3 (needs Rr==64).
template<int TI>
DEV void transpose_body(const float* __restrict__ in, unsigned short* __restrict__ out,
                        int Rr, int Cc, int bx, int by, int bz, int tid, char* sbuf) {
  unsigned short (*tile)[33] = (unsigned short (*)[33])sbuf;
  const float* ib = in + (long)bz * Rr * Cc;
  unsigned short* ob = out + (long)bz * Rr * Cc;
  int r0 = by * 32, c0 = bx * 32;
  int tr = tid >> 5, tc = tid & 31;
#pragma unroll
  for (int i = 0; i < 4; ++i) {
    int r = tr + i * 8;
    tile[r][tc] = f2bf(ib[(long)(r0 + r) * Cc + c0 + tc]);
  }
  __syncthreads();
#pragma unroll
  for (int i = 0; i < 4; ++i) {
    int c = tr + i * 8;
    int row = c0 + c;
    int k = r0 + tc;
    if (TI == 0) ob[(long)row * Rr + k] = tile[tc][c];
    else ob[(long)row * Rr + (k ^ ((row & 7) << 3))] = tile[tc][c];
  }
}

// big convert+transpose for pin/pout: in [Rr k][Cc n] fp32 -> out tiled bf16 [n][k].
DEV void trans_big_body(const float* __restrict__ in, unsigned short* __restrict__ out,
                        int Rr, int Cc, int bx, int by, int bz, int tid, char* sbuf) {
  float (*t)[64] = (float (*)[64])sbuf;
  const float* ib = in + (long)bz * Rr * Cc;
  unsigned short* ob = out + (long)bz * (long)Rr * Cc;
  int k0 = by * 64, n0 = bx * 64;
#pragma unroll
  for (int p = 0; p < 4; ++p) {
    int idx = p * 256 + tid;
    int kr = idx >> 4, nc = (idx & 15) * 4;
    *(float4*)&t[kr][nc] = *(const float4*)(ib + (long)(k0 + kr) * Cc + n0 + nc);
  }
  __syncthreads();
#pragma unroll
  for (int p = 0; p < 2; ++p) {
    int idx = p * 256 + tid;
    int n = idx & 63, kc = idx >> 6;       // kc 0..7
    float v[8];
#pragma unroll
    for (int u = 0; u < 8; ++u) v[u] = t[kc * 8 + u][n];
    uint4 o;
    o.x = pk2bf(v[0], v[1]); o.y = pk2bf(v[2], v[3]);
    o.z = pk2bf(v[4], v[5]); o.w = pk2bf(v[6], v[7]);
    *(uint4*)(ob + tiled_off(n0 + n, k0 + kc * 8, Rr)) = o;
  }
}

// ONE dispatch for all prep: blocks 0..2047 pinT, 2048..4095 poutT,
// 4096..4607 wgT, 4608..5119 wuT, 5120..5631 wdT, 5632 geoprep.
__global__ __launch_bounds__(256) void prep_k(
    const float* __restrict__ pin, const float* __restrict__ pout,
    const float* __restrict__ fg, const float* __restrict__ fu,
    const float* __restrict__ fd, const float* __restrict__ iw,
    const float* __restrict__ gg,
    unsigned short* __restrict__ pinT, unsigned short* __restrict__ poutT,
    unsigned short* __restrict__ wgT, unsigned short* __restrict__ wuT,
    unsigned short* __restrict__ wdT, float* __restrict__ wcomb) {
  __shared__ char sbuf[16384];
  int b = blockIdx.x, tid = threadIdx.x;
  if (b < 2048) {
    trans_big_body(pin, pinT, 1024, 512, b & 7, (b >> 3) & 15, b >> 7, tid, sbuf);
  } else if (b < 4096) {
    int j = b - 2048;
    trans_big_body(pout, poutT, 512, 1024, j & 15, (j >> 4) & 7, j >> 7, tid, sbuf);
  } else if (b < 4608) {
    int j = b - 4096;
    transpose_body<1>(fg, wgT, 64, 256, j & 7, (j >> 3) & 1, j >> 4, tid, sbuf);
  } else if (b < 5120) {
    int j = b - 4608;
    transpose_body<1>(fu, wuT, 64, 256, j & 7, (j >> 3) & 1, j >> 4, tid, sbuf);
  } else if (b < 5632) {
    int j = b - 5120;
    transpose_body<0>(fd, wdT, 256, 64, j & 1, (j >> 1) & 7, j >> 4, tid, sbuf);
  } else {
    if (tid < 32) geoprep_body(iw, gg, wcomb, tid);
  }
}

// GEMM1 (convert FUSED): mvB(bf16, linear [token][512]) = x @ Pin^T per expert.
// 256x256 tile, BK=64 in two 32-sub-phases. B staged via async16 from tiled
// pinT; A staged from x fp32 directly (reg-load -> cvt -> ds_write, T14 split).
__global__ __launch_bounds__(512, 1) void gemm_in_k(const float* __restrict__ X,
                                                    const unsigned short* __restrict__ Bw,
                                                    unsigned short* __restrict__ MvB,
                                                    const int* __restrict__ offs) {
  extern __shared__ char smem[];    // [2 buf][ A 32K | B 32K ], each op as 2 x 16K ksub
  int bid = blockIdx.x;             // 256 blocks
  int wg = (bid & 7) * 32 + (bid >> 3);      // XCD swizzle (256 % 8 == 0)
  int e = wg >> 4, rem = wg & 15, bm = rem >> 1, bn = rem & 1;
  int tid = threadIdx.x, wid = tid >> 6, lane = tid & 63;
  int wm = (wid >> 2) * 128, wn = (wid & 3) * 64;
  int ri = lane & 15, hi = lane >> 4;
  long rowbase = (long)offs[e] + bm * 256;   // A row base (x fp32 linear)
  long bw = (long)e * 64 + bn * 32;          // B window base (pinT tiled, K=1024)

  // phase p = t*2+s (t=K-tile 0..15, s=32-k sub 0..1)
  auto STGB = [&](int p) {
    int t = p >> 1, s = p & 1, b = t & 1;
    char* dst = smem + b * 65536 + 32768 + s * 16384;
#pragma unroll
    for (int i = 0; i < 2; ++i) {
      int d = i * 512 + tid;
      async16(Bw + (bw + (d >> 5)) * 8192 +
                  (long)((t * 8 + s * 4 + ((d >> 3) & 3)) * 64 + (d & 7) * 8),
              (unsigned short*)(dst + d * 16));
    }
  };
  auto A_LOAD = [&](int p, float4 ar[2][2]) {
    int t = p >> 1, s = p & 1;
#pragma unroll
    for (int i = 0; i < 2; ++i) {
      int d = i * 512 + tid;
      const float* src = X + (rowbase + ((d >> 5) * 8 + (d & 7))) * 1024 +
                         t * 64 + s * 32 + ((d >> 3) & 3) * 8;
      ar[i][0] = *(const float4*)src;
      ar[i][1] = *(const float4*)(src + 4);
    }
  };
  auto A_WRITE = [&](int p, float4 ar[2][2]) {
    int t = p >> 1, s = p & 1, b = t & 1;
    char* dst = smem + b * 65536 + s * 16384;
#pragma unroll
    for (int i = 0; i < 2; ++i) {
      int d = i * 512 + tid;
      uint4 o;
      o.x = pk2bf(ar[i][0].x, ar[i][0].y);
      o.y = pk2bf(ar[i][0].z, ar[i][0].w);
      o.z = pk2bf(ar[i][1].x, ar[i][1].y);
      o.w = pk2bf(ar[i][1].z, ar[i][1].w);
      *(uint4*)(dst + d * 16) = o;
    }
  };

  f32x4 acc[8][4];
#pragma unroll
  for (int i = 0; i < 8; ++i)
#pragma unroll
    for (int j = 0; j < 4; ++j) acc[i][j] = (f32x4){0.f, 0.f, 0.f, 0.f};

  // prologue: phases 0 and 1 staged (A via regs, B via async16)
  float4 ar[2][2];
  A_LOAD(0, ar); STGB(0); STGB(1);
  A_WRITE(0, ar);                 // compiler auto-waits the A regs
  A_LOAD(1, ar);
  A_WRITE(1, ar);
  wait_lgkm0();

#pragma unroll 2
  for (int p = 0; p < 32; ++p) {
    int t = p >> 1, s = p & 1, c = t & 1;
    if (p < 30) { A_LOAD(p + 2, ar); STGB(p + 2); }
    if (p < 30) asm volatile("s_waitcnt vmcnt(8)" ::: "memory");
    else if (p == 30) asm volatile("s_waitcnt vmcnt(2)" ::: "memory");
    else asm volatile("s_waitcnt vmcnt(0)" ::: "memory");
    sbar();
    const char* cA = smem + c * 65536 + s * 16384;
    const char* cB = smem + c * 65536 + 32768 + s * 16384;
    bf16x8 a[8], b[4];
#pragma unroll
    for (int i = 0; i < 8; ++i) a[i] = ld_frag(cA, wm + i * 16 + ri, hi);
#pragma unroll
    for (int j = 0; j < 4; ++j) b[j] = ld_frag(cB, wn + j * 16 + ri, hi);
    __builtin_amdgcn_s_setprio(1);
#pragma unroll
    for (int i = 0; i < 8; ++i)
#pragma unroll
      for (int j = 0; j < 4; ++j)
        acc[i][j] = __builtin_amdgcn_mfma_f32_16x16x32_bf16(a[i], b[j], acc[i][j], 0, 0, 0);
    __builtin_amdgcn_s_setprio(0);
    if (p < 30) A_WRITE(p + 2, ar);
    wait_lgkm0();
  }

  unsigned short* Cb = MvB + ((long)e * 2048 + (long)bm * 256) * 512 + bn * 256;
#pragma unroll
  for (int i = 0; i < 8; ++i)
#pragma unroll
    for (int j = 0; j < 4; ++j)
#pragma unroll
      for (int rr = 0; rr < 4; ++rr)
        Cb[(long)(wm + i * 16 + hi * 4 + rr) * 512 + wn + j * 16 + ri] =
            f2bf1(acc[i][j][rr]);
}

// ---------- merged 2-round fused kernel: 4 TOK/WAVE + REG RESIDUAL ----------
// 16 tokens/block, 256 threads = 4 waves; each wave owns 4 tokens (32 trows,
// 2 trow-tiles). r10 lesson: reg-residual at 8tok is ARITHMETICALLY infeasible
// (live set ~210 > cap 170 -> forced spill, twice). At 4tok it fits:
// persistent uv 16 + acc2 32 + bfr 16 = 64; peak ~130 < 170 at (256,3).
// LDS only 32K (sFH 16K + sW 16K; NO sMv) -> hardware can schedule 4-5
// blocks/CU when actual VGPR <= 128/102 (launch_bounds sets the MINIMUM).
// Residual in uint2 uv[8] (bf16-packed, SSA access only). P5 frag->token
// transpose through sFH (dead after last P4): write bf16 deltas, lgkm, read
// in (t4,q) layout, add in regs.
//   sFH  @0     16K: 4 waves x 4K [32 row][128B] xor swz (flat -> h -> P5 scr)
//   sW   @16K   16K: dbuf x (Wg 4K | Wu 4K) eighth (swizzle baked in global)
__global__ __launch_bounds__(256, 3) void rounds_k(
    const unsigned short* __restrict__ MvB, const unsigned short* __restrict__ WgT,
    const unsigned short* __restrict__ WuT, const unsigned short* __restrict__ WdT,
    const float* __restrict__ wcomb, const float* __restrict__ lnw,
    const float* __restrict__ lnb, unsigned short* __restrict__ Mvb) {
  extern __shared__ char smem[];
  int tid = threadIdx.x, wid = tid >> 6, lane = tid & 63;
  char* sFH = smem + wid * 4096;            // wave-private [32 row][128B]
  char* sW  = smem + 16384;                 // dbuf 2 x 8K (Wg 4K | Wu 4K)

  int bid = blockIdx.x;
  int wg = (bid & 7) * 256 + (bid >> 3);    // XCD swizzle (2048 % 8 == 0)
  int e = wg >> 7, bx = wg & 127;

  int t4 = lane >> 4, q = lane & 15;        // P1/P5 coords: token-in-wave, d-quad
  int ri = lane & 15, hi = lane >> 4;       // frag coords
  int sw = (ri & 7) << 4;

  // stage global eighth i8 (0..15; round = i8>>3, slice = i8&7)
  auto STAGE = [&](int i8) {
    long base = (long)(e * 2 + (i8 >> 3)) * 16384 + (i8 & 7) * 2048;
    char* dst = sW + (i8 & 1) * 8192;
    async16(WgT + base + tid * 8, (unsigned short*)(dst + tid * 16));
    async16(WuT + base + tid * 8, (unsigned short*)(dst + 4096 + tid * 16));
  };
  STAGE(0);   // prologue: lands under P1 of round 0

  // ---- persistent residual in regs: uv[i] = (token t4, blade i, d 4q..4q+3) ----
  uint2 uv[8];
  {
    long base = ((long)e * 2048 + bx * 16 + wid * 4 + t4) * 512 + 4 * q;
#pragma unroll
    for (int i = 0; i < 8; ++i)
      uv[i] = *(const uint2*)(MvB + base + i * 64);
  }

#pragma unroll 1
  for (int r = 0; r < 2; ++r) {
    int er = e * 2 + r;
    const unsigned short* wd = WdT + (long)er * 16384;  // [64 dout][256 F]

    // ---- P1a: unpack reg-resident mv ----
    f32x4 mv[8];
#pragma unroll
    for (int i = 0; i < 8; ++i)
      mv[i] = (f32x4){bf2f((unsigned short)(uv[i].x & 0xffff)),
                      bf2f((unsigned short)(uv[i].x >> 16)),
                      bf2f((unsigned short)(uv[i].y & 0xffff)),
                      bf2f((unsigned short)(uv[i].y >> 16))};

    // ---- P1b: geo + mix + LN(64) -> sFH (packed f32x4 math; wave-private) ----
    {
      const float* C = wcomb + er * 40;
      f32x4 g[8];
#pragma unroll
      for (int k = 0; k < 8; ++k) g[k] = (f32x4){0.f, 0.f, 0.f, 0.f};
#pragma unroll
      for (int i = 0; i < 8; ++i)
#pragma unroll
        for (int j = i; j < 8; ++j) {
          float cc = C[PIDX(i, j)];
          const int k = KIDX(i, j);
          g[k] += cc * (mv[i] * mv[j]);
        }
      float omg = C[36];
#pragma unroll
      for (int k = 0; k < 8; ++k) g[k] = omg * mv[k] + g[k];
      float4 lw = *(const float4*)(lnw + (long)er * 64 + 4 * q);
      float4 lb = *(const float4*)(lnb + (long)er * 64 + 4 * q);
      f32x4 lwv = (f32x4){lw.x, lw.y, lw.z, lw.w};
      f32x4 lbv = (f32x4){lb.x, lb.y, lb.z, lb.w};
#pragma unroll
      for (int half = 0; half < 2; ++half) {
        f32x2 red[4];
#pragma unroll
        for (int k = 0; k < 4; ++k) {
          f32x4 m = g[half * 4 + k];
          red[k].x = (m.x + m.y) + (m.z + m.w);
          red[k].y = fmaf(m.x, m.x, m.y * m.y) + fmaf(m.z, m.z, m.w * m.w);
        }
#pragma unroll
        for (int off = 8; off >= 1; off >>= 1)
#pragma unroll
          for (int t = 0; t < 4; ++t) {
            f32x2 o;
            o.x = __shfl_xor(red[t].x, off);
            o.y = __shfl_xor(red[t].y, off);
            red[t] += o;
          }
#pragma unroll
        for (int k = 0; k < 4; ++k) {
          int kk = half * 4 + k;
          float mean = red[k].x * (1.f / 64.f);
          float var = red[k].y * (1.f / 64.f) - mean * mean;
          float rs = rsqrtf(var + 1e-5f);
          f32x4 nv = (g[kk] - mean) * rs;
          f32x4 ov = nv * lwv + lbv;
          uint2 pv;
          pv.x = pk2bf(ov.x, ov.y);
          pv.y = pk2bf(ov.z, ov.w);
          int row = t4 * 8 + kk;                    // row&7 == kk
          *(uint2*)(sFH + row * 128 + ((8 * q) ^ (kk << 4))) = pv;
        }
      }
    }
    wait_lgkm0();   // own-wave flat writes done (cross-LANE reads next)

    // ---- hoist flat B-frags to regs (sFH gets reused for h afterwards) ----
    bf16x8 bfr[2][2];   // [trow-tile][k-half]
#pragma unroll
    for (int tt = 0; tt < 2; ++tt)
#pragma unroll
      for (int kt = 0; kt < 2; ++kt)
        bfr[tt][kt] = *(const bf16x8*)(sFH + (tt * 16 + ri) * 128 + ((kt * 64 + hi * 16) ^ sw));

    f32x4 acc2[4][2];   // [dout-tile][trow-tile]
#pragma unroll
    for (int j = 0; j < 4; ++j)
#pragma unroll
      for (int tt = 0; tt < 2; ++tt) acc2[j][tt] = (f32x4){0.f, 0.f, 0.f, 0.f};

#pragma unroll 1
    for (int q8 = 0; q8 < 8; ++q8) {
      int i8 = r * 8 + q8;
      wait_vm0();   // stage(i8) landed (issued a full eighth ago)
      sbar();       // all waves: stage(i8) in LDS; eighth i8-1 reads done
      if (i8 < 15) STAGE(i8 + 1);   // -> buf((i8+1)&1): free per the barrier

      // ---- Wd frags at PHASE TOP (global; full-phase latency cover) ----
      bf16x8 wdf[4];
#pragma unroll
      for (int j = 0; j < 4; ++j)
        wdf[j] = *(const bf16x8*)(wd + (j * 16 + ri) * 256 + q8 * 32 + hi * 8);

      const char* bufW = sW + (i8 & 1) * 8192;

      // ---- P2: 2 F-tiles x 2 trow-tiles; silu -> h ----
#pragma unroll
      for (int ftl = 0; ftl < 2; ++ftl) {
        const char* bg = bufW + (ftl * 16 + ri) * 128;
        const char* bu = bg + 4096;
        bf16x8 wg0 = *(const bf16x8*)(bg + ((hi * 16) ^ sw));
        bf16x8 wg1 = *(const bf16x8*)(bg + ((64 + hi * 16) ^ sw));
        bf16x8 wu0 = *(const bf16x8*)(bu + ((hi * 16) ^ sw));
        bf16x8 wu1 = *(const bf16x8*)(bu + ((64 + hi * 16) ^ sw));
        f32x4 ag[2], au[2];
#pragma unroll
        for (int tt = 0; tt < 2; ++tt) {
          ag[tt] = (f32x4){0.f, 0.f, 0.f, 0.f};
          au[tt] = (f32x4){0.f, 0.f, 0.f, 0.f};
        }
        __builtin_amdgcn_s_setprio(1);
#pragma unroll
        for (int tt = 0; tt < 2; ++tt) {
          ag[tt] = __builtin_amdgcn_mfma_f32_16x16x32_bf16(wg0, bfr[tt][0], ag[tt], 0, 0, 0);
          au[tt] = __builtin_amdgcn_mfma_f32_16x16x32_bf16(wu0, bfr[tt][0], au[tt], 0, 0, 0);
          ag[tt] = __builtin_amdgcn_mfma_f32_16x16x32_bf16(wg1, bfr[tt][1], ag[tt], 0, 0, 0);
          au[tt] = __builtin_amdgcn_mfma_f32_16x16x32_bf16(wu1, bfr[tt][1], au[tt], 0, 0, 0);
        }
        __builtin_amdgcn_s_setprio(0);
#pragma unroll
        for (int tt = 0; tt < 2; ++tt) {
          float hh[4];
#pragma unroll
          for (int rr = 0; rr < 4; ++rr) {
            float gv = ag[tt][rr], uu = au[tt][rr];
            hh[rr] = gv * uu * frcp(1.f + __expf(-gv));
          }
          uint2 hwv;
          hwv.x = pk2bf(hh[0], hh[1]);
          hwv.y = pk2bf(hh[2], hh[3]);
          // h (F_loc = ftl*16+hi*4+rr, trow = tt*16+ri) -> swizzled
          *(uint2*)(sFH + (tt * 16 + ri) * 128 + ((ftl * 32 + hi * 8) ^ sw)) = hwv;
        }
      }
      wait_lgkm0();  // own h writes complete before hk reads

      // ---- P4: acc2[dout][trow-tile] += Wd x h (one 32-k chunk) ----
      bf16x8 hk0 = *(const bf16x8*)(sFH + ri * 128 + ((hi * 16) ^ sw));
      bf16x8 hk1 = *(const bf16x8*)(sFH + (16 + ri) * 128 + ((hi * 16) ^ sw));
      __builtin_amdgcn_s_setprio(1);
#pragma unroll
      for (int j = 0; j < 4; ++j)
        acc2[j][0] = __builtin_amdgcn_mfma_f32_16x16x32_bf16(wdf[j], hk0, acc2[j][0], 0, 0, 0);
#pragma unroll
      for (int j = 0; j < 4; ++j)
        acc2[j][1] = __builtin_amdgcn_mfma_f32_16x16x32_bf16(wdf[j], hk1, acc2[j][1], 0, 0, 0);
      __builtin_amdgcn_s_setprio(0);
    }

    // ---- P5: delta transpose through sFH (h dead), then SSA reg residual add ----
    {
#pragma unroll
      for (int tt = 0; tt < 2; ++tt) {
        int tl = tt * 2 + (ri >> 3);   // token 0..3
        int kb = ri & 7;               // blade
#pragma unroll
        for (int j = 0; j < 4; ++j) {
          uint2 dv;
          dv.x = pk2bf(acc2[j][tt][0], acc2[j][tt][1]);
          dv.y = pk2bf(acc2[j][tt][2], acc2[j][tt][3]);
          // delta (token tl, blade kb, d = j*16+hi*4 .. +3), row&7 == kb
          *(uint2*)(sFH + (tl * 8 + kb) * 128 + ((j * 32 + hi * 8) ^ (kb << 4))) = dv;
        }
      }
      wait_lgkm0();
#pragma unroll
      for (int i = 0; i < 8; ++i) {
        uint2 dv = *(const uint2*)(sFH + (t4 * 8 + i) * 128 + ((8 * q) ^ (i << 4)));
        uv[i].x = addbf2(uv[i].x, dv.x);
        uv[i].y = addbf2(uv[i].y, dv.y);
      }
    }
    wait_lgkm0();   // readbacks done before next round's P1b overwrites sFH

    // ---- r1: dump reg residual -> Mvb (linear [token][512]) ----
    if (r == 1) {
      long row = (long)e * 2048 + bx * 16 + wid * 4 + t4;
      unsigned short* dst = Mvb + row * 512 + 4 * q;
#pragma unroll
      for (int i = 0; i < 8; ++i)
        *(uint2*)(dst + i * 64) = uv[i];
    }
  }
}

// ---------- fused out-projection + LayerNorm(D=1024), 512 threads/block ----------
// A (mvb) is LINEAR [token][512] bf16; tiled LDS layout derived via per-lane source addr.
__global__ __launch_bounds__(512, 2) void gemm_out_ln_k(
    const unsigned short* __restrict__ Mvb, const unsigned short* __restrict__ Pw,
    float* __restrict__ Out, const float* __restrict__ ow, const float* __restrict__ ob,
    const int* __restrict__ offs) {
  extern __shared__ char smem[];
  int bid = blockIdx.x;
  int wg = (bid & 7) * 64 + (bid >> 3);
  int e = wg >> 5, mb = wg & 31;
  int tid = threadIdx.x, wid = tid >> 6, lane = tid & 63;
  int ri = lane & 15, hi = lane >> 4;
  long bbase = (long)e * 524288;                 // poutT expert base (tiled)
  long arow0 = (long)e * 2048 + (long)mb * 64;   // mvb expert row base (linear)

  auto STAGE = [&](int buf, int kt) {
#pragma unroll
    for (int i = 0; i < 8; ++i) {
      int q = i * 512 + tid;
      int w = q >> 5, c = (q >> 3) & 3, rr = q & 7;
      async16(Pw + bbase + (long)w * 4096 + (kt * 4 + c) * 64 + rr * 8,
              (unsigned short*)(smem + buf * 65536 + q * 16));
    }
    if (tid < 256) {
      int q = tid;
      int w = q >> 5, c = (q >> 3) & 3, rr = q & 7;
      async16(Mvb + (arow0 + w * 8 + rr) * 512 + kt * 32 + c * 8,
              (unsigned short*)(smem + 131072 + buf * 4096 + q * 16));
    }
  };

  f32x4 acc[4][8];
#pragma unroll
  for (int i = 0; i < 4; ++i)
#pragma unroll
    for (int j = 0; j < 8; ++j) acc[i][j] = (f32x4){0.f, 0.f, 0.f, 0.f};

  STAGE(0, 0);
  for (int kt = 0; kt < 16; ++kt) {
    int cur = kt & 1;
    if (kt < 15) {
      STAGE(cur ^ 1, kt + 1);
      asm volatile("s_waitcnt vmcnt(8)" ::: "memory");
    } else {
      asm volatile("s_waitcnt vmcnt(0)" ::: "memory");
    }
    sbar();
    const char* cB = smem + cur * 65536;
    const char* cA = smem + 131072 + cur * 4096;
    bf16x8 a[4], b[8];
#pragma unroll
    for (int i = 0; i < 4; ++i) a[i] = ld_frag(cA, i * 16 + ri, hi);
#pragma unroll
    for (int j = 0; j < 8; ++j) b[j] = ld_frag(cB, wid * 128 + j * 16 + ri, hi);
    __builtin_amdgcn_s_setprio(1);
#pragma unroll
    for (int i = 0; i < 4; ++i)
#pragma unroll
      for (int j = 0; j < 8; ++j)
        acc[i][j] = __builtin_amdgcn_mfma_f32_16x16x32_bf16(a[i], b[j], acc[i][j], 0, 0, 0);
    __builtin_amdgcn_s_setprio(0);
    sbar();
  }

  float* rsum = (float*)(smem + 139264);
  float* rsq  = (float*)(smem + 141312);
  float* mexp = (float*)(smem + 143360);
  float* rstd = (float*)(smem + 143616);
  int hi4 = hi * 4;
#pragma unroll
  for (int i = 0; i < 4; ++i)
#pragma unroll
    for (int rr = 0; rr < 4; ++rr) {
      float s = 0.f, qv = 0.f;
#pragma unroll
      for (int j = 0; j < 8; ++j) { float v = acc[i][j][rr]; s += v; qv += v * v; }
#pragma unroll
      for (int off = 1; off < 16; off <<= 1) {
        s += __shfl_xor(s, off);
        qv += __shfl_xor(qv, off);
      }
      if (ri == 0) {
        int row = i * 16 + hi4 + rr;
        rsum[row * 8 + wid] = s;
        rsq[row * 8 + wid] = qv;
      }
    }
  __syncthreads();
  if (tid < 64) {
    float S = 0.f, Q = 0.f;
#pragma unroll
    for (int w = 0; w < 8; ++w) { S += rsum[tid * 8 + w]; Q += rsq[tid * 8 + w]; }
    float mean = S * (1.f / 1024.f);
    float var = Q * (1.f / 1024.f) - mean * mean;
    mexp[tid] = mean;
    rstd[tid] = rsqrtf(var + 1e-5f);
  }
  __syncthreads();
  long r0 = (long)offs[e] + (long)mb * 64;
  float owv[8], obv[8];
#pragma unroll
  for (int j = 0; j < 8; ++j) {
    int col = wid * 128 + j * 16 + ri;
    owv[j] = ow[col];
    obv[j] = ob[col];
  }
#pragma unroll
  for (int i = 0; i < 4; ++i)
#pragma unroll
    for (int rr = 0; rr < 4; ++rr) {
      int row = i * 16 + hi4 + rr;
      float mu = mexp[row], rs = rstd[row];
#pragma unroll
      for (int j = 0; j < 8; ++j) {
        int col = wid * 128 + j * 16 + ri;
        Out[(r0 + row) * 1024 + col] = (acc[i][j][rr] - mu) * rs * owv[j] + obv[j];
      }
    }
}

// ---------- host ----------
extern "C" void kernel_launch(void* const* d_in, const int* in_sizes, int n_in,
                              void* d_out, int out_size, void* d_ws, size_t ws_size,
                              hipStream_t stream) {
  const float* x    = (const float*)d_in[0];
  const float* pin  = (const float*)d_in[1];
  const float* pout = (const float*)d_in[2];
  const float* iw   = (const float*)d_in[3];
  const float* gg   = (const float*)d_in[4];
  const float* fg   = (const float*)d_in[5];
  const float* fu   = (const float*)d_in[6];
  const float* fd   = (const float*)d_in[7];
  const float* lnw  = (const float*)d_in[8];
  const float* lnb  = (const float*)d_in[9];
  const float* ow   = (const float*)d_in[10];
  const float* ob   = (const float*)d_in[11];
  const int* offs   = (const int*)d_in[12];

  char* ws = (char*)d_ws;
  unsigned short* mvB  = (unsigned short*)(ws + 0L);          //  33,554,432 B (linear bf16)
  unsigned short* mvb  = (unsigned short*)(ws + 33554432L);   //  33,554,432 B (linear bf16)
  unsigned short* pinT = (unsigned short*)(ws + 67108864L);   //  16,777,216 B (tiled)
  unsigned short* poutT= (unsigned short*)(ws + 83886080L);   //  16,777,216 B (tiled)
  unsigned short* wgT  = (unsigned short*)(ws + 100663296L);  //   2,097,152 B (swz-64)
  unsigned short* wuT  = (unsigned short*)(ws + 102760448L);  //   2,097,152 B (swz-64)
  unsigned short* wdT  = (unsigned short*)(ws + 104857600L);  //   2,097,152 B (plain)
  float* wcomb         = (float*)(ws + 106954752L);           //   5,120 B

  // ALL prep in ONE dispatch
  prep_k<<<dim3(5633), dim3(256), 0, stream>>>(
      pin, pout, fg, fu, fd, iw, gg, pinT, poutT, wgT, wuT, wdT, wcomb);

  // mvB = x @ Pin (A fp32->bf16 reg-staged in-kernel; B from tiled pinT)
  gemm_in_k<<<dim3(256), dim3(512), 131072, stream>>>(x, pinT, mvB, offs);

  // both rounds in ONE kernel; 4 tok/wave, reg residual, 32K LDS
  rounds_k<<<dim3(2048), dim3(256), 32768, stream>>>(
      mvB, wgT, wuT, wdT, wcomb, lnw, lnb, mvb);

  // out = LN(mvb @ Pout)
  gemm_out_ln_k<<<dim3(512), dim3(512), 143872, stream>>>(
      mvb, poutT, (float*)d_out, ow, ob, offs);
}

// Round 12
// 253.315 us; speedup vs baseline: 1.2385x; 1.0273x over previous
//
#include <hip/hip_runtime.h>

#define DEV __device__ __forceinline__

typedef __attribute__((ext_vector_type(4))) float f32x4;
typedef __attribute__((ext_vector_type(2))) float f32x2;
typedef __attribute__((ext_vector_type(8))) short bf16x8;

// Shapes: E=16, D=1024, ED=512, NB=8, DB=64, R=2, F=256, N=32768, C=2048

// ---------- helpers ----------
DEV unsigned short f2bf(float f) {
  union { float f; unsigned u; } v; v.f = f;
  unsigned r = v.u + 0x7fffu + ((v.u >> 16) & 1u);
  return (unsigned short)(r >> 16);
}

DEV unsigned pk2bf(float lo, float hi) {  // v_cvt_pk_bf16_f32 (RNE)
  unsigned r;
  asm("v_cvt_pk_bf16_f32 %0, %1, %2" : "=v"(r) : "v"(lo), "v"(hi));
  return r;
}
DEV unsigned short f2bf1(float v) { return (unsigned short)pk2bf(v, v); }

DEV float bf2f(unsigned short b) {
  union { unsigned u; float f; } v; v.u = ((unsigned)b) << 16; return v.f;
}

DEV float frcp(float x) { return __builtin_amdgcn_rcpf(x); }

// raw barrier: NO implicit vmcnt drain. "memory" clobber = compiler fence.
DEV void sbar() { asm volatile("s_barrier" ::: "memory"); }
DEV void wait_lgkm0() { asm volatile("s_waitcnt lgkmcnt(0)" ::: "memory"); }
DEV void wait_vm0() { asm volatile("s_waitcnt vmcnt(0)" ::: "memory"); }

DEV void async16(const unsigned short* g, unsigned short* l) {
  __builtin_amdgcn_global_load_lds(
      (__attribute__((address_space(1))) const unsigned int*)g,
      (__attribute__((address_space(3))) unsigned int*)l, 16, 0, 0);
}

// Tiled global layout for GEMM operands: element (n,k) of an [N][K] panel at
//   (n>>3)*8K + (k>>3)*64 + (n&7)*8 + (k&7)
DEV long tiled_off(long n, int k, int K) {
  return (n >> 3) * (8L * K) + (long)(((k >> 3) * 64) + ((int)(n & 7)) * 8 + (k & 7));
}

// frag read from a tiled 32-k LDS subtile (bf16)
DEV bf16x8 ld_frag(const char* s, int row, int hi) {
  return *(const bf16x8*)(s + ((row >> 3) * 512 + hi * 128 + (row & 7) * 16));
}

// ---------- Cayley table at compile time ----------
__host__ __device__ constexpr int km_(int i) { return i==0?0:i==1?1:i==2?2:i==3?4:i==4?3:i==5?5:i==6?6:7; }
__host__ __device__ constexpr int pc_(int x) { int c = 0; while (x) { c += x & 1; x >>= 1; } return c; }
__host__ __device__ constexpr int KIDX(int i, int j) { return km_(km_(i) ^ km_(j)); }
__host__ __device__ constexpr int CSGN(int i, int j) {
  int a = km_(i), b = km_(j), aa = a >> 1, s = 0;
  while (aa) { s += pc_(aa & b); aa >>= 1; }
  return (s & 1) ? -1 : 1;
}
__host__ __device__ constexpr int PIDX(int i, int j) {  // i<=j
  return 8 * i - (i * (i - 1)) / 2 + (j - i);
}

// ---------- prep bodies (merged into ONE dispatch) ----------

DEV void geoprep_body(const float* __restrict__ iw, const float* __restrict__ gg,
                      float* __restrict__ wcomb, int er) {
  const float* w = iw + er * 64;
  float gate = frcp(1.f + __expf(-gg[er]));
  float* c = wcomb + er * 40;
  int p = 0;
  for (int i = 0; i < 8; ++i)
    for (int j = i; j < 8; ++j) {
      float v = (float)CSGN(i, j) * frcp(1.f + __expf(-w[i * 8 + j]));
      if (j > i) v += (float)CSGN(j, i) * frcp(1.f + __expf(-w[j * 8 + i]));
      c[p++] = gate * v;
    }
  c[36] = 1.f - gate;
}

// small transpose: in (Rr,Cc) fp32 (batch bz) -> (Cc,Rr) bf16.
// TI=0 linear; TI=1: k ^= (row&7)<<3 (needs Rr==64).
template<int TI>
DEV void transpose_body(const float* __restrict__ in, unsigned short* __restrict__ out,
                        int Rr, int Cc, int bx, int by, int bz, int tid, char* sbuf) {
  unsigned short (*tile)[33] = (unsigned short (*)[33])sbuf;
  const float* ib = in + (long)bz * Rr * Cc;
  unsigned short* ob = out + (long)bz * Rr * Cc;
  int r0 = by * 32, c0 = bx * 32;
  int tr = tid >> 5, tc = tid & 31;
#pragma unroll
  for (int i = 0; i < 4; ++i) {
    int r = tr + i * 8;
    tile[r][tc] = f2bf(ib[(long)(r0 + r) * Cc + c0 + tc]);
  }
  __syncthreads();
#pragma unroll
  for (int i = 0; i < 4; ++i) {
    int c = tr + i * 8;
    int row = c0 + c;
    int k = r0 + tc;
    if (TI == 0) ob[(long)row * Rr + k] = tile[tc][c];
    else ob[(long)row * Rr + (k ^ ((row & 7) << 3))] = tile[tc][c];
  }
}

// big convert+transpose for pin/pout: in [Rr k][Cc n] fp32 -> out tiled bf16 [n][k].
DEV void trans_big_body(const float* __restrict__ in, unsigned short* __restrict__ out,
                        int Rr, int Cc, int bx, int by, int bz, int tid, char* sbuf) {
  float (*t)[64] = (float (*)[64])sbuf;
  const float* ib = in + (long)bz * Rr * Cc;
  unsigned short* ob = out + (long)bz * (long)Rr * Cc;
  int k0 = by * 64, n0 = bx * 64;
#pragma unroll
  for (int p = 0; p < 4; ++p) {
    int idx = p * 256 + tid;
    int kr = idx >> 4, nc = (idx & 15) * 4;
    *(float4*)&t[kr][nc] = *(const float4*)(ib + (long)(k0 + kr) * Cc + n0 + nc);
  }
  __syncthreads();
#pragma unroll
  for (int p = 0; p < 2; ++p) {
    int idx = p * 256 + tid;
    int n = idx & 63, kc = idx >> 6;       // kc 0..7
    float v[8];
#pragma unroll
    for (int u = 0; u < 8; ++u) v[u] = t[kc * 8 + u][n];
    uint4 o;
    o.x = pk2bf(v[0], v[1]); o.y = pk2bf(v[2], v[3]);
    o.z = pk2bf(v[4], v[5]); o.w = pk2bf(v[6], v[7]);
    *(uint4*)(ob + tiled_off(n0 + n, k0 + kc * 8, Rr)) = o;
  }
}

// ONE dispatch for all prep: blocks 0..2047 pinT, 2048..4095 poutT,
// 4096..4607 wgT, 4608..5119 wuT, 5120..5631 wdT, 5632 geoprep.
__global__ __launch_bounds__(256) void prep_k(
    const float* __restrict__ pin, const float* __restrict__ pout,
    const float* __restrict__ fg, const float* __restrict__ fu,
    const float* __restrict__ fd, const float* __restrict__ iw,
    const float* __restrict__ gg,
    unsigned short* __restrict__ pinT, unsigned short* __restrict__ poutT,
    unsigned short* __restrict__ wgT, unsigned short* __restrict__ wuT,
    unsigned short* __restrict__ wdT, float* __restrict__ wcomb) {
  __shared__ char sbuf[16384];
  int b = blockIdx.x, tid = threadIdx.x;
  if (b < 2048) {
    trans_big_body(pin, pinT, 1024, 512, b & 7, (b >> 3) & 15, b >> 7, tid, sbuf);
  } else if (b < 4096) {
    int j = b - 2048;
    trans_big_body(pout, poutT, 512, 1024, j & 15, (j >> 4) & 7, j >> 7, tid, sbuf);
  } else if (b < 4608) {
    int j = b - 4096;
    transpose_body<1>(fg, wgT, 64, 256, j & 7, (j >> 3) & 1, j >> 4, tid, sbuf);
  } else if (b < 5120) {
    int j = b - 4608;
    transpose_body<1>(fu, wuT, 64, 256, j & 7, (j >> 3) & 1, j >> 4, tid, sbuf);
  } else if (b < 5632) {
    int j = b - 5120;
    transpose_body<0>(fd, wdT, 256, 64, j & 1, (j >> 1) & 7, j >> 4, tid, sbuf);
  } else {
    if (tid < 32) geoprep_body(iw, gg, wcomb, tid);
  }
}

// GEMM1 (convert fused): mvB(bf16, linear [token][512]) = x @ Pin^T per expert.
// 256x256 tile, BK=64 in two 32-sub-phases. B staged via async16 from tiled
// pinT; A staged from x fp32 via regs (load -> cvt -> ds_write).
// r12: A prefetch deepened to TWO phases (r0-r11: A_LOAD(p+2) at phase-p top,
// consumed by A_WRITE(p+2) at phase-p END -> ~350cy cover vs ~900cy HBM miss;
// all 8 barrier-synced waves convoyed on the A-wait every phase). Now:
// ping-pong regs, A_LOAD(p+3) at top, A_WRITE(p+2) (loaded a phase earlier)
// after MFMA. LDS slot for p+2 is disjoint from p/p+1 reads; prior readers
// (phase p-2) are 2 barriers back. Queue at phase top (steady) = 14:
// B(p)2,A(p+2)4,B(p+1)2,A(p+3)4,B(p+2)2 -> drain B(p) with vmcnt(12);
// tail: p==29 -> 8, p==30 -> 2, p==31 -> 0.
__global__ __launch_bounds__(512, 1) void gemm_in_k(const float* __restrict__ X,
                                                    const unsigned short* __restrict__ Bw,
                                                    unsigned short* __restrict__ MvB,
                                                    const int* __restrict__ offs) {
  extern __shared__ char smem[];    // [2 buf][ A 32K | B 32K ], each op as 2 x 16K ksub
  int bid = blockIdx.x;             // 256 blocks
  int wg = (bid & 7) * 32 + (bid >> 3);      // XCD swizzle (256 % 8 == 0)
  int e = wg >> 4, rem = wg & 15, bm = rem >> 1, bn = rem & 1;
  int tid = threadIdx.x, wid = tid >> 6, lane = tid & 63;
  int wm = (wid >> 2) * 128, wn = (wid & 3) * 64;
  int ri = lane & 15, hi = lane >> 4;
  long rowbase = (long)offs[e] + bm * 256;   // A row base (x fp32 linear)
  long bw = (long)e * 64 + bn * 32;          // B window base (pinT tiled, K=1024)

  // phase p = t*2+s (t=K-tile 0..15, s=32-k sub 0..1)
  auto STGB = [&](int p) {
    int t = p >> 1, s = p & 1, b = t & 1;
    char* dst = smem + b * 65536 + 32768 + s * 16384;
#pragma unroll
    for (int i = 0; i < 2; ++i) {
      int d = i * 512 + tid;
      async16(Bw + (bw + (d >> 5)) * 8192 +
                  (long)((t * 8 + s * 4 + ((d >> 3) & 3)) * 64 + (d & 7) * 8),
              (unsigned short*)(dst + d * 16));
    }
  };
  auto A_LOAD = [&](int p, float4 ar[2][2]) {
    int t = p >> 1, s = p & 1;
#pragma unroll
    for (int i = 0; i < 2; ++i) {
      int d = i * 512 + tid;
      const float* src = X + (rowbase + ((d >> 5) * 8 + (d & 7))) * 1024 +
                         t * 64 + s * 32 + ((d >> 3) & 3) * 8;
      ar[i][0] = *(const float4*)src;
      ar[i][1] = *(const float4*)(src + 4);
    }
  };
  auto A_WRITE = [&](int p, float4 ar[2][2]) {
    int t = p >> 1, s = p & 1, b = t & 1;
    char* dst = smem + b * 65536 + s * 16384;
#pragma unroll
    for (int i = 0; i < 2; ++i) {
      int d = i * 512 + tid;
      uint4 o;
      o.x = pk2bf(ar[i][0].x, ar[i][0].y);
      o.y = pk2bf(ar[i][0].z, ar[i][0].w);
      o.z = pk2bf(ar[i][1].x, ar[i][1].y);
      o.w = pk2bf(ar[i][1].z, ar[i][1].w);
      *(uint4*)(dst + d * 16) = o;
    }
  };

  f32x4 acc[8][4];
#pragma unroll
  for (int i = 0; i < 8; ++i)
#pragma unroll
    for (int j = 0; j < 4; ++j) acc[i][j] = (f32x4){0.f, 0.f, 0.f, 0.f};

  // prologue: A(0),A(1) written; A(2) in flight; B(0),B(1) staged+drained.
  float4 ar0[2][2], ar1[2][2];
  A_LOAD(0, ar0); STGB(0); STGB(1);
  A_WRITE(0, ar0);                // implicit wait on A(0)
  A_LOAD(1, ar1);
  A_WRITE(1, ar1);                // implicit wait drains B(0),B(1) too (once)
  A_LOAD(2, ar0);                 // lands by end of phase 0
  wait_lgkm0();

#pragma unroll 2
  for (int p = 0; p < 32; ++p) {
    int t = p >> 1, s = p & 1, c = t & 1;
    if (p < 29) { if (p & 1) A_LOAD(p + 3, ar0); else A_LOAD(p + 3, ar1); }
    if (p < 30) STGB(p + 2);
    if (p < 29) asm volatile("s_waitcnt vmcnt(12)" ::: "memory");
    else if (p == 29) asm volatile("s_waitcnt vmcnt(8)" ::: "memory");
    else if (p == 30) asm volatile("s_waitcnt vmcnt(2)" ::: "memory");
    else asm volatile("s_waitcnt vmcnt(0)" ::: "memory");
    sbar();
    const char* cA = smem + c * 65536 + s * 16384;
    const char* cB = smem + c * 65536 + 32768 + s * 16384;
    bf16x8 a[8], b[4];
#pragma unroll
    for (int i = 0; i < 8; ++i) a[i] = ld_frag(cA, wm + i * 16 + ri, hi);
#pragma unroll
    for (int j = 0; j < 4; ++j) b[j] = ld_frag(cB, wn + j * 16 + ri, hi);
    __builtin_amdgcn_s_setprio(1);
#pragma unroll
    for (int i = 0; i < 8; ++i)
#pragma unroll
      for (int j = 0; j < 4; ++j)
        acc[i][j] = __builtin_amdgcn_mfma_f32_16x16x32_bf16(a[i], b[j], acc[i][j], 0, 0, 0);
    __builtin_amdgcn_s_setprio(0);
    if (p < 30) { if (p & 1) A_WRITE(p + 2, ar1); else A_WRITE(p + 2, ar0); }
    wait_lgkm0();
  }

  unsigned short* Cb = MvB + ((long)e * 2048 + (long)bm * 256) * 512 + bn * 256;
#pragma unroll
  for (int i = 0; i < 8; ++i)
#pragma unroll
    for (int j = 0; j < 4; ++j)
#pragma unroll
      for (int rr = 0; rr < 4; ++rr)
        Cb[(long)(wm + i * 16 + hi * 4 + rr) * 512 + wn + j * 16 + ri] =
            f2bf1(acc[i][j][rr]);
}

// ---------- merged 2-round fused kernel: 8 TOKENS PER WAVE ----------
// (r8's proven version: 114.7us, MfmaUtil 18, VGPR 104, no spill. r11 showed
// occupancy is NOT the limiter -> keep this structure frozen.)
__global__ __launch_bounds__(256, 2) void rounds_k(
    const unsigned short* __restrict__ MvB, const unsigned short* __restrict__ WgT,
    const unsigned short* __restrict__ WuT, const unsigned short* __restrict__ WdT,
    const float* __restrict__ wcomb, const float* __restrict__ lnw,
    const float* __restrict__ lnb, unsigned short* __restrict__ Mvb) {
  extern __shared__ char smem[];
  int tid = threadIdx.x, wid = tid >> 6, lane = tid & 63;
  char* sFH = smem + wid * 8192;            // wave-private [64 trow][128B]
  char* sMv = smem + 32768 + wid * 8192;    // wave-private [8 tok][1K]
  char* sW  = smem + 65536;                 // dbuf 2 x 8K (Wg 4K | Wu 4K)

  int bid = blockIdx.x;
  int wg = (bid & 7) * 128 + (bid >> 3);    // XCD swizzle (1024 % 8 == 0)
  int e = wg >> 6, bx = wg & 63;

  int t8 = lane >> 3, q = lane & 7;         // P1 coords: token-in-wave, d-octet
  int ri = lane & 15, hi = lane >> 4;       // frag coords
  int sw = (ri & 7) << 4;

  // stage global eighth i8 (0..15; round = i8>>3, slice = i8&7)
  auto STAGE = [&](int i8) {
    long base = (long)(e * 2 + (i8 >> 3)) * 16384 + (i8 & 7) * 2048;
    char* dst = sW + (i8 & 1) * 8192;
    async16(WgT + base + tid * 8, (unsigned short*)(dst + tid * 16));
    async16(WuT + base + tid * 8, (unsigned short*)(dst + 4096 + tid * 16));
  };
  STAGE(0);   // prologue: lands under P1 of round 0

#pragma unroll 1
  for (int r = 0; r < 2; ++r) {
    int er = e * 2 + r;
    const unsigned short* wd = WdT + (long)er * 16384;  // [64 dout][256 F]

    // ---- P1a: mv (global bf16 on r0 -> stash to sMvh; sMvh on r1) ----
    // Each lane: token t8, d = 8q..8q+7 (two f32x4 halves).
    f32x4 mv[2][8];
    if (r == 0) {
      long base = ((long)e * 2048 + bx * 32 + wid * 8 + t8) * 512 + 8 * q;
      uint4 uv[8];
#pragma unroll
      for (int i = 0; i < 8; ++i)
        uv[i] = *(const uint4*)(MvB + base + i * 64);
#pragma unroll
      for (int i = 0; i < 8; ++i) {
        *(uint4*)(sMv + t8 * 1024 + i * 128 + ((16 * q) ^ (i << 4))) = uv[i];
        mv[0][i] = (f32x4){bf2f((unsigned short)(uv[i].x & 0xffff)),
                           bf2f((unsigned short)(uv[i].x >> 16)),
                           bf2f((unsigned short)(uv[i].y & 0xffff)),
                           bf2f((unsigned short)(uv[i].y >> 16))};
        mv[1][i] = (f32x4){bf2f((unsigned short)(uv[i].z & 0xffff)),
                           bf2f((unsigned short)(uv[i].z >> 16)),
                           bf2f((unsigned short)(uv[i].w & 0xffff)),
                           bf2f((unsigned short)(uv[i].w >> 16))};
      }
    } else {
#pragma unroll
      for (int i = 0; i < 8; ++i) {
        uint4 uv = *(const uint4*)(sMv + t8 * 1024 + i * 128 + ((16 * q) ^ (i << 4)));
        mv[0][i] = (f32x4){bf2f((unsigned short)(uv.x & 0xffff)),
                           bf2f((unsigned short)(uv.x >> 16)),
                           bf2f((unsigned short)(uv.y & 0xffff)),
                           bf2f((unsigned short)(uv.y >> 16))};
        mv[1][i] = (f32x4){bf2f((unsigned short)(uv.z & 0xffff)),
                           bf2f((unsigned short)(uv.z >> 16)),
                           bf2f((unsigned short)(uv.w & 0xffff)),
                           bf2f((unsigned short)(uv.w >> 16))};
      }
    }

    // ---- P1b: geo + mix + LN(64) -> sFH (packed math; wave-private) ----
    {
      const float* C = wcomb + er * 40;
      f32x4 g[2][8];
#pragma unroll
      for (int hf = 0; hf < 2; ++hf)
#pragma unroll
        for (int k = 0; k < 8; ++k) g[hf][k] = (f32x4){0.f, 0.f, 0.f, 0.f};
#pragma unroll
      for (int i = 0; i < 8; ++i)
#pragma unroll
        for (int j = i; j < 8; ++j) {
          float cc = C[PIDX(i, j)];
          const int k = KIDX(i, j);
          g[0][k] += cc * (mv[0][i] * mv[0][j]);
          g[1][k] += cc * (mv[1][i] * mv[1][j]);
        }
      float omg = C[36];
#pragma unroll
      for (int hf = 0; hf < 2; ++hf)
#pragma unroll
        for (int k = 0; k < 8; ++k) g[hf][k] = omg * mv[hf][k] + g[hf][k];
      float4 lwa = *(const float4*)(lnw + (long)er * 64 + 8 * q);
      float4 lwb = *(const float4*)(lnw + (long)er * 64 + 8 * q + 4);
      float4 lba = *(const float4*)(lnb + (long)er * 64 + 8 * q);
      float4 lbb = *(const float4*)(lnb + (long)er * 64 + 8 * q + 4);
      f32x4 lwvA = (f32x4){lwa.x, lwa.y, lwa.z, lwa.w};
      f32x4 lwvB = (f32x4){lwb.x, lwb.y, lwb.z, lwb.w};
      f32x4 lbvA = (f32x4){lba.x, lba.y, lba.z, lba.w};
      f32x4 lbvB = (f32x4){lbb.x, lbb.y, lbb.z, lbb.w};
#pragma unroll
      for (int bh = 0; bh < 2; ++bh) {
        f32x2 red[4];
#pragma unroll
        for (int k = 0; k < 4; ++k) {
          f32x4 a = g[0][bh * 4 + k], b = g[1][bh * 4 + k];
          red[k].x = ((a.x + a.y) + (a.z + a.w)) + ((b.x + b.y) + (b.z + b.w));
          red[k].y = (fmaf(a.x, a.x, a.y * a.y) + fmaf(a.z, a.z, a.w * a.w)) +
                     (fmaf(b.x, b.x, b.y * b.y) + fmaf(b.z, b.z, b.w * b.w));
        }
#pragma unroll
        for (int off = 4; off >= 1; off >>= 1)
#pragma unroll
          for (int t = 0; t < 4; ++t) {
            f32x2 o;
            o.x = __shfl_xor(red[t].x, off);
            o.y = __shfl_xor(red[t].y, off);
            red[t] += o;
          }
#pragma unroll
        for (int k = 0; k < 4; ++k) {
          int kk = bh * 4 + k;
          float mean = red[k].x * (1.f / 64.f);
          float var = red[k].y * (1.f / 64.f) - mean * mean;
          float rs = rsqrtf(var + 1e-5f);
          f32x4 ovA = ((g[0][kk] - mean) * rs) * lwvA + lbvA;
          f32x4 ovB = ((g[1][kk] - mean) * rs) * lwvB + lbvB;
          uint4 pv;
          pv.x = pk2bf(ovA.x, ovA.y);
          pv.y = pk2bf(ovA.z, ovA.w);
          pv.z = pk2bf(ovB.x, ovB.y);
          pv.w = pk2bf(ovB.z, ovB.w);
          int row = t8 * 8 + kk;                    // row&7 == kk
          *(uint4*)(sFH + row * 128 + ((16 * q) ^ (kk << 4))) = pv;
        }
      }
    }
    wait_lgkm0();   // own-wave flat writes done (cross-LANE reads next)

    // ---- hoist flat B-frags to regs (sFH gets reused for h afterwards) ----
    bf16x8 bfr[4][2];   // [trow-tile][k-half]
#pragma unroll
    for (int tt = 0; tt < 4; ++tt)
#pragma unroll
      for (int kt = 0; kt < 2; ++kt)
        bfr[tt][kt] = *(const bf16x8*)(sFH + (tt * 16 + ri) * 128 + ((kt * 64 + hi * 16) ^ sw));

    f32x4 acc2[4][4];   // [dout-tile][trow-tile]
#pragma unroll
    for (int j = 0; j < 4; ++j)
#pragma unroll
      for (int tt = 0; tt < 4; ++tt) acc2[j][tt] = (f32x4){0.f, 0.f, 0.f, 0.f};

#pragma unroll 1
    for (int q8 = 0; q8 < 8; ++q8) {
      int i8 = r * 8 + q8;
      wait_vm0();   // stage(i8) landed (issued a full eighth ago)
      sbar();       // all waves: stage(i8) in LDS; eighth i8-1 reads done
      if (i8 < 15) STAGE(i8 + 1);   // -> buf((i8+1)&1): free per the barrier

      // ---- Wd frags at PHASE TOP (global; full-phase latency cover) ----
      bf16x8 wdf[4];
#pragma unroll
      for (int j = 0; j < 4; ++j)
        wdf[j] = *(const bf16x8*)(wd + (j * 16 + ri) * 256 + q8 * 32 + hi * 8);

      const char* bufW = sW + (i8 & 1) * 8192;

      // ---- P2: 2 F-tiles x 4 trow-tiles; silu -> h ----
#pragma unroll
      for (int ftl = 0; ftl < 2; ++ftl) {
        const char* bg = bufW + (ftl * 16 + ri) * 128;
        const char* bu = bg + 4096;
        bf16x8 wg0 = *(const bf16x8*)(bg + ((hi * 16) ^ sw));
        bf16x8 wg1 = *(const bf16x8*)(bg + ((64 + hi * 16) ^ sw));
        bf16x8 wu0 = *(const bf16x8*)(bu + ((hi * 16) ^ sw));
        bf16x8 wu1 = *(const bf16x8*)(bu + ((64 + hi * 16) ^ sw));
        f32x4 ag[4], au[4];
#pragma unroll
        for (int tt = 0; tt < 4; ++tt) {
          ag[tt] = (f32x4){0.f, 0.f, 0.f, 0.f};
          au[tt] = (f32x4){0.f, 0.f, 0.f, 0.f};
        }
        __builtin_amdgcn_s_setprio(1);
#pragma unroll
        for (int tt = 0; tt < 4; ++tt) {
          ag[tt] = __builtin_amdgcn_mfma_f32_16x16x32_bf16(wg0, bfr[tt][0], ag[tt], 0, 0, 0);
          au[tt] = __builtin_amdgcn_mfma_f32_16x16x32_bf16(wu0, bfr[tt][0], au[tt], 0, 0, 0);
          ag[tt] = __builtin_amdgcn_mfma_f32_16x16x32_bf16(wg1, bfr[tt][1], ag[tt], 0, 0, 0);
          au[tt] = __builtin_amdgcn_mfma_f32_16x16x32_bf16(wu1, bfr[tt][1], au[tt], 0, 0, 0);
        }
        __builtin_amdgcn_s_setprio(0);
#pragma unroll
        for (int tt = 0; tt < 4; ++tt) {
          float hh[4];
#pragma unroll
          for (int rr = 0; rr < 4; ++rr) {
            float gv = ag[tt][rr], uu = au[tt][rr];
            hh[rr] = gv * uu * frcp(1.f + __expf(-gv));
          }
          uint2 hwv;
          hwv.x = pk2bf(hh[0], hh[1]);
          hwv.y = pk2bf(hh[2], hh[3]);
          // h (F_loc = ftl*16+hi*4+rr, trow = tt*16+ri) -> swizzled
          *(uint2*)(sFH + (tt * 16 + ri) * 128 + ((ftl * 32 + hi * 8) ^ sw)) = hwv;
        }
      }
      wait_lgkm0();  // own h writes complete before hk reads

      // ---- P4: acc2[dout][trow-tile] += Wd x h (one 32-k chunk) ----
      bf16x8 hk[4];
#pragma unroll
      for (int tt = 0; tt < 4; ++tt)
        hk[tt] = *(const bf16x8*)(sFH + (tt * 16 + ri) * 128 + ((hi * 16) ^ sw));
      __builtin_amdgcn_s_setprio(1);
#pragma unroll
      for (int j = 0; j < 4; ++j)
#pragma unroll
        for (int tt = 0; tt < 4; ++tt)
          acc2[j][tt] = __builtin_amdgcn_mfma_f32_16x16x32_bf16(wdf[j], hk[tt], acc2[j][tt], 0, 0, 0);
      __builtin_amdgcn_s_setprio(0);
    }

    // ---- P5: residual vs sMvh (wave-private, in place both rounds) ----
    {
#pragma unroll
      for (int tt = 0; tt < 4; ++tt) {
        int tl = tt * 2 + (ri >> 3);
        int kb = ri & 7;
#pragma unroll
        for (int j = 0; j < 4; ++j)
#pragma unroll
          for (int u = 0; u < 2; ++u) {
            int off = (j * 32 + hi * 8 + 4 * u) ^ sw;
            unsigned* p = (unsigned*)(sMv + tl * 1024 + kb * 128 + off);
            unsigned old = *p;
            float v0 = bf2f((unsigned short)(old & 0xffff)) + acc2[j][tt][2 * u];
            float v1 = bf2f((unsigned short)(old >> 16)) + acc2[j][tt][2 * u + 1];
            *p = pk2bf(v0, v1);
          }
      }
    }
    wait_lgkm0();   // sMvh updates done (next round's P1a / epilogue reads)

    // ---- r1: coalesced uint4 dump sMvh -> Mvb (8 rows = 8KB contiguous) ----
    if (r == 1) {
      int bl = lane >> 3, qq = lane & 7;
      long sbase = ((long)e * 2048 + bx * 32 + wid * 8) * 512;
#pragma unroll
      for (int h = 0; h < 8; ++h) {
        uint4 v = *(const uint4*)(sMv + h * 1024 + bl * 128 + ((16 * qq) ^ (bl << 4)));
        *(uint4*)(Mvb + sbase + h * 512 + lane * 8) = v;
      }
    }
  }
}

// ---------- fused out-projection + LayerNorm(D=1024), 512 threads/block ----------
// A (mvb) is LINEAR [token][512] bf16; tiled LDS layout derived via per-lane source addr.
__global__ __launch_bounds__(512, 2) void gemm_out_ln_k(
    const unsigned short* __restrict__ Mvb, const unsigned short* __restrict__ Pw,
    float* __restrict__ Out, const float* __restrict__ ow, const float* __restrict__ ob,
    const int* __restrict__ offs) {
  extern __shared__ char smem[];
  int bid = blockIdx.x;
  int wg = (bid & 7) * 64 + (bid >> 3);
  int e = wg >> 5, mb = wg & 31;
  int tid = threadIdx.x, wid = tid >> 6, lane = tid & 63;
  int ri = lane & 15, hi = lane >> 4;
  long bbase = (long)e * 524288;                 // poutT expert base (tiled)
  long arow0 = (long)e * 2048 + (long)mb * 64;   // mvb expert row base (linear)

  auto STAGE = [&](int buf, int kt) {
#pragma unroll
    for (int i = 0; i < 8; ++i) {
      int q = i * 512 + tid;
      int w = q >> 5, c = (q >> 3) & 3, rr = q & 7;
      async16(Pw + bbase + (long)w * 4096 + (kt * 4 + c) * 64 + rr * 8,
              (unsigned short*)(smem + buf * 65536 + q * 16));
    }
    if (tid < 256) {
      int q = tid;
      int w = q >> 5, c = (q >> 3) & 3, rr = q & 7;
      async16(Mvb + (arow0 + w * 8 + rr) * 512 + kt * 32 + c * 8,
              (unsigned short*)(smem + 131072 + buf * 4096 + q * 16));
    }
  };

  f32x4 acc[4][8];
#pragma unroll
  for (int i = 0; i < 4; ++i)
#pragma unroll
    for (int j = 0; j < 8; ++j) acc[i][j] = (f32x4){0.f, 0.f, 0.f, 0.f};

  STAGE(0, 0);
  for (int kt = 0; kt < 16; ++kt) {
    int cur = kt & 1;
    if (kt < 15) {
      STAGE(cur ^ 1, kt + 1);
      asm volatile("s_waitcnt vmcnt(8)" ::: "memory");
    } else {
      asm volatile("s_waitcnt vmcnt(0)" ::: "memory");
    }
    sbar();
    const char* cB = smem + cur * 65536;
    const char* cA = smem + 131072 + cur * 4096;
    bf16x8 a[4], b[8];
#pragma unroll
    for (int i = 0; i < 4; ++i) a[i] = ld_frag(cA, i * 16 + ri, hi);
#pragma unroll
    for (int j = 0; j < 8; ++j) b[j] = ld_frag(cB, wid * 128 + j * 16 + ri, hi);
    __builtin_amdgcn_s_setprio(1);
#pragma unroll
    for (int i = 0; i < 4; ++i)
#pragma unroll
      for (int j = 0; j < 8; ++j)
        acc[i][j] = __builtin_amdgcn_mfma_f32_16x16x32_bf16(a[i], b[j], acc[i][j], 0, 0, 0);
    __builtin_amdgcn_s_setprio(0);
    sbar();
  }

  float* rsum = (float*)(smem + 139264);
  float* rsq  = (float*)(smem + 141312);
  float* mexp = (float*)(smem + 143360);
  float* rstd = (float*)(smem + 143616);
  int hi4 = hi * 4;
#pragma unroll
  for (int i = 0; i < 4; ++i)
#pragma unroll
    for (int rr = 0; rr < 4; ++rr) {
      float s = 0.f, qv = 0.f;
#pragma unroll
      for (int j = 0; j < 8; ++j) { float v = acc[i][j][rr]; s += v; qv += v * v; }
#pragma unroll
      for (int off = 1; off < 16; off <<= 1) {
        s += __shfl_xor(s, off);
        qv += __shfl_xor(qv, off);
      }
      if (ri == 0) {
        int row = i * 16 + hi4 + rr;
        rsum[row * 8 + wid] = s;
        rsq[row * 8 + wid] = qv;
      }
    }
  __syncthreads();
  if (tid < 64) {
    float S = 0.f, Q = 0.f;
#pragma unroll
    for (int w = 0; w < 8; ++w) { S += rsum[tid * 8 + w]; Q += rsq[tid * 8 + w]; }
    float mean = S * (1.f / 1024.f);
    float var = Q * (1.f / 1024.f) - mean * mean;
    mexp[tid] = mean;
    rstd[tid] = rsqrtf(var + 1e-5f);
  }
  __syncthreads();
  long r0 = (long)offs[e] + (long)mb * 64;
  float owv[8], obv[8];
#pragma unroll
  for (int j = 0; j < 8; ++j) {
    int col = wid * 128 + j * 16 + ri;
    owv[j] = ow[col];
    obv[j] = ob[col];
  }
#pragma unroll
  for (int i = 0; i < 4; ++i)
#pragma unroll
    for (int rr = 0; rr < 4; ++rr) {
      int row = i * 16 + hi4 + rr;
      float mu = mexp[row], rs = rstd[row];
#pragma unroll
      for (int j = 0; j < 8; ++j) {
        int col = wid * 128 + j * 16 + ri;
        Out[(r0 + row) * 1024 + col] = (acc[i][j][rr] - mu) * rs * owv[j] + obv[j];
      }
    }
}

// ---------- host ----------
extern "C" void kernel_launch(void* const* d_in, const int* in_sizes, int n_in,
                              void* d_out, int out_size, void* d_ws, size_t ws_size,
                              hipStream_t stream) {
  const float* x    = (const float*)d_in[0];
  const float* pin  = (const float*)d_in[1];
  const float* pout = (const float*)d_in[2];
  const float* iw   = (const float*)d_in[3];
  const float* gg   = (const float*)d_in[4];
  const float* fg   = (const float*)d_in[5];
  const float* fu   = (const float*)d_in[6];
  const float* fd   = (const float*)d_in[7];
  const float* lnw  = (const float*)d_in[8];
  const float* lnb  = (const float*)d_in[9];
  const float* ow   = (const float*)d_in[10];
  const float* ob   = (const float*)d_in[11];
  const int* offs   = (const int*)d_in[12];

  char* ws = (char*)d_ws;
  unsigned short* mvB  = (unsigned short*)(ws + 0L);          //  33,554,432 B (linear bf16)
  unsigned short* mvb  = (unsigned short*)(ws + 33554432L);   //  33,554,432 B (linear bf16)
  unsigned short* pinT = (unsigned short*)(ws + 67108864L);   //  16,777,216 B (tiled)
  unsigned short* poutT= (unsigned short*)(ws + 83886080L);   //  16,777,216 B (tiled)
  unsigned short* wgT  = (unsigned short*)(ws + 100663296L);  //   2,097,152 B (swz-64)
  unsigned short* wuT  = (unsigned short*)(ws + 102760448L);  //   2,097,152 B (swz-64)
  unsigned short* wdT  = (unsigned short*)(ws + 104857600L);  //   2,097,152 B (plain)
  float* wcomb         = (float*)(ws + 106954752L);           //   5,120 B

  // ALL prep in ONE dispatch
  prep_k<<<dim3(5633), dim3(256), 0, stream>>>(
      pin, pout, fg, fu, fd, iw, gg, pinT, poutT, wgT, wuT, wdT, wcomb);

  // mvB = x @ Pin (A fp32->bf16 reg-staged, 2-phase prefetch; B from tiled pinT)
  gemm_in_k<<<dim3(256), dim3(512), 131072, stream>>>(x, pinT, mvB, offs);

  // both rounds in ONE kernel; 8 tokens/wave, W dbuf in eighths, 80K LDS
  rounds_k<<<dim3(1024), dim3(256), 81920, stream>>>(
      mvB, wgT, wuT, wdT, wcomb, lnw, lnb, mvb);

  // out = LN(mvb @ Pout)
  gemm_out_ln_k<<<dim3(512), dim3(512), 143872, stream>>>(
      mvb, poutT, (float*)d_out, ow, ob, offs);
}